// Round 21
// baseline (216.985 us; speedup 1.0000x reference)
//
#include <hip/hip_runtime.h>

// KacLayer: out[512][4096] = x @ W^T + b  +  Kac2( vec * Kac1( x ) )
//
//  kfused: blocks 0..11: per-8192-step window scheduler. Depth election v2:
//          key = step id; winners CLEAR their columns and set wflag[col]=rr;
//          pending steps re-stamp only when a column was cleared last round
//          (stamps persist as valid minima) -> ~6x fewer LDS atomics than
//          round-stamped keys. Per-wave chunk streams (levels <=2 chunks
//          serial on wave0, barrier elision). Exact emission via u16 inverse
//          permutation. Bit-exact reorder of commuting Givens rotations.
//          blocks 12..1163: fp32->bf16 convert of W and X into d_ws.
//  kboth : ONE launch, blocks 0..255 = walk path (4 waves / row-pair,
//          level-parallel, light barriers, s_setprio(1) hot loop), blocks
//          256.. = GEMM path (128x128, BK=64, global_load_lds staging,
//          swizzled LDS, Ksplit=2 -> 1 walk + 1 GEMM block per CU).
//  kadd  : out = gemm_out + walkbuf + partial.

#define DIM    4096
#define ROWS   512
#define NSTEPS 49152
#define WSTEPS 8192
#define NW2    (NSTEPS / WSTEPS)   // 6 windows per walk
#define NSLOT  (2 * NW2)           // 12 slots
#define NSG    16                  // rank subgroups (one per ksched wave)
#define CHUNK  128
#define WVN    4                   // walk waves per block
#define PWC    96                  // per-wave chunk capacity per slot
#define SLOTREC (WVN * PWC * CHUNK)   // 49152 records per slot
#define MAXR   96
#define PADI   4096
#define PADJ   4097
#define KT     1024                // scheduler threads
#define SPT    (WSTEPS / KT)       // 8 steps per thread
#define NCVW   1024                // W-convert blocks
#define NCVX   128                 // X-convert blocks
#define SMEMB  33664               // kboth shared bytes (walk needs 33168)
#define INVCAP ((DIM + WSTEPS) * 2)   // 24576 u16 entries = 192 chunks

typedef short  short8 __attribute__((ext_vector_type(8)));
typedef __bf16 bf16x8 __attribute__((ext_vector_type(8)));
typedef float  f32x4  __attribute__((ext_vector_type(4)));

__device__ inline short f2bf(float f) {
    unsigned u = __builtin_bit_cast(unsigned, f);
    u += 0x7FFFu + ((u >> 16) & 1u);
    return (short)(u >> 16);
}
__device__ inline short8 pack8(float4 a, float4 b) {
    short8 r;
    r[0] = f2bf(a.x); r[1] = f2bf(a.y); r[2] = f2bf(a.z); r[3] = f2bf(a.w);
    r[4] = f2bf(b.x); r[5] = f2bf(b.y); r[6] = f2bf(b.z); r[7] = f2bf(b.w);
    return r;
}
__device__ inline float bitf(unsigned u) { return __builtin_bit_cast(float, u); }
__device__ inline float2 ldrw(const float2* rw, int boff) {
    return *(const float2*)((const char*)rw + boff);
}
__device__ inline void strw(float2* rw, int boff, float2 v) {
    *(float2*)((char*)rw + boff) = v;
}
__device__ inline void gl16(const short* g, short* l) {
    __builtin_amdgcn_global_load_lds((const __attribute__((address_space(1))) unsigned*)g,
                                     (__attribute__((address_space(3))) unsigned*)l, 16, 0, 0);
}

// ---------------------------------------------------------------------------
// 1) fused scheduler (blocks 0..NSLOT-1) + bf16 convert (blocks NSLOT..)
// ---------------------------------------------------------------------------
__global__ __launch_bounds__(KT) void kfused(
    const int* __restrict__ i1, const int* __restrict__ j1,
    const float* __restrict__ c1, const float* __restrict__ s1,
    const int* __restrict__ i2, const int* __restrict__ j2,
    const float* __restrict__ c2, const float* __restrict__ s2,
    uint4* __restrict__ recs, int* __restrict__ nlvls, unsigned* __restrict__ lvmeta_g,
    int doconv, const float* __restrict__ W, const float* __restrict__ X,
    short* __restrict__ wb, short* __restrict__ xb) {

    if (blockIdx.x >= NSLOT) {
        if (!doconv) return;
        const int cb = blockIdx.x - NSLOT;
        const float* src; short* dst; size_t base;
        if (cb < NCVW) { src = W; dst = wb; base = (size_t)cb * 16384; }
        else           { src = X; dst = xb; base = (size_t)(cb - NCVW) * 16384; }
        const size_t o = base + (size_t)threadIdx.x * 16;
        const float4* s4 = (const float4*)(src + o);
        const float4 a0 = s4[0], a1 = s4[1], a2 = s4[2], a3 = s4[3];
        *(short8*)(dst + o)     = pack8(a0, a1);
        *(short8*)(dst + o + 8) = pack8(a2, a3);
        return;
    }

    __shared__ unsigned pool[DIM + WSTEPS];      // 48 KB (tbl+spair; then inv)
    __shared__ unsigned lvrk[WSTEPS];            // 32 KB: rank<<8 | level
    __shared__ int wflag[DIM];                   // 16 KB: round col last cleared
    __shared__ int lcnt[MAXR * NSG];             // 6 KB
    __shared__ unsigned lvpk[MAXR], wvbase[MAXR];
    __shared__ unsigned char serf[MAXR];
    __shared__ int nlvlsh;
    __shared__ unsigned totpk;
    __shared__ int ucnt4[WVN], sbase4[WVN];

    unsigned* tbl   = pool;
    unsigned* spair = pool + DIM;

    const int b    = blockIdx.x;
    const int walk = b / NW2;
    const int w    = b % NW2;
    const int t    = threadIdx.x;
    const int gb   = w * WSTEPS;
    const int sg   = t >> 6;

    const int*   I = walk ? i2 : i1;
    const int*   J = walk ? j2 : j1;
    const float* C = walk ? c2 : c1;
    const float* S = walk ? s2 : s1;

    uint4* slotp = recs + (size_t)b * SLOTREC;

    for (int s = t; s < WSTEPS; s += KT)
        spair[s] = (unsigned)I[gb + s] | ((unsigned)J[gb + s] << 16);
    for (int k = t; k < DIM; k += KT) { tbl[k] = 0xFFFFFFFFu; wflag[k] = -1; }
    for (int k = t; k < MAXR * NSG; k += KT) lcnt[k] = 0;
    if (t < MAXR) serf[t] = 0;
    if (t == 0) nlvlsh = 1;
    __syncthreads();

    // ---- election v2: lazy stamp + clear-on-win; level = DAG depth --------
    unsigned pmask = (1u << SPT) - 1u;
    for (int rr = 0; rr < MAXR; ++rr) {
        // stamp phase: only steps whose column was cleared last round
#pragma unroll
        for (int q = 0; q < SPT; ++q)
            if (pmask & (1u << q)) {
                const int s = q * KT + t;
                const unsigned sp = spair[s];
                const int li = (int)(sp & 0xFFFFu), lj = (int)(sp >> 16);
                if (rr == 0 || wflag[li] == rr - 1 || wflag[lj] == rr - 1) {
                    atomicMin(&tbl[li], (unsigned)s);
                    atomicMin(&tbl[lj], (unsigned)s);
                }
            }
        __syncthreads();                                   // B1
        // check phase: winner = min stamped on BOTH cols; clear + flag
#pragma unroll
        for (int q = 0; q < SPT; ++q)
            if (pmask & (1u << q)) {
                const int s = q * KT + t;
                const unsigned sp = spair[s];
                const int li = (int)(sp & 0xFFFFu), lj = (int)(sp >> 16);
                if (tbl[li] == (unsigned)s && tbl[lj] == (unsigned)s) {
                    const int rank = atomicAdd(&lcnt[rr * NSG + sg], 1);
                    lvrk[s] = ((unsigned)rank << 8) | (unsigned)rr;
                    pmask &= ~(1u << q);
                    tbl[li] = 0xFFFFFFFFu; tbl[lj] = 0xFFFFFFFFu;  // winner's cols
                    wflag[li] = rr; wflag[lj] = rr;
                }
            }
        const int np = __syncthreads_count(pmask != 0);    // B2
        if (np == 0) break;
    }
#pragma unroll
    for (int q = 0; q < SPT; ++q)
        if (pmask & (1u << q)) {       // statistically unreachable
            const int s = q * KT + t;
            const int rank = atomicAdd(&lcnt[(MAXR - 1) * NSG + sg], 1);
            lvrk[s] = ((unsigned)rank << 8) | (unsigned)(MAXR - 1);
        }
    __syncthreads();

    // ---- layout -----------------------------------------------------------
    if (t < MAXR) {
        int run = 0;
        for (int g = 0; g < NSG; ++g) {
            const int v = lcnt[t * NSG + g];
            lcnt[t * NSG + g] = run;
            run += v;
        }
        const int nch = (run + 127) >> 7;
        unsigned pk = 0;
        if (run > 0 && nch <= 2) { serf[t] = 1; pk = (unsigned)nch; }
        else {
#pragma unroll
            for (int wv = 0; wv < WVN; ++wv)
                pk |= (unsigned)((nch + (WVN - 1 - wv)) >> 2) << (8 * wv);
        }
        lvpk[t] = pk;
        if (run > 0) atomicMax(&nlvlsh, t + 1);
    }
    __syncthreads();
    if (t < 64) {
        const int l = t;
        const unsigned w1 = lvpk[l];
        unsigned x1 = w1;
        for (int off = 1; off < 64; off <<= 1) {
            const unsigned v = (unsigned)__shfl_up((int)x1, off);
            if (l >= off) x1 += v;
        }
        wvbase[l] = x1 - w1;
        const unsigned seg1 = (unsigned)__shfl((int)x1, 63);
        const int l2 = 64 + (l & 31);
        const unsigned w2 = lvpk[l2];
        unsigned x2 = w2;
        for (int off = 1; off < 32; off <<= 1) {
            const unsigned v = (unsigned)__shfl_up((int)x2, off);
            if ((l & 31) >= off) x2 += v;
        }
        if (l < 32) wvbase[l2] = seg1 + x2 - w2;
        if (l == 31) totpk = seg1 + x2;
    }
    __syncthreads();
    if (t < WVN) {
        int u = (int)((totpk >> (8 * t)) & 0xFFu);
        ucnt4[t] = (u > PWC) ? PWC : u;
    }
    if (t < MAXR - 1) {
        if (serf[t] && serf[t + 1]) lvpk[t] |= 0x80000000u;
    }
    __syncthreads();
    if (t == 0) {
        sbase4[0] = 0;
        for (int v = 1; v < WVN; ++v) sbase4[v] = sbase4[v - 1] + ucnt4[v - 1];
        nlvls[b] = nlvlsh;
    }
    if (t < MAXR) lvmeta_g[b * MAXR + t] = lvpk[t];
    __syncthreads();

    // ---- inv table over used positions (reuses pool) ----------------------
    const int usedtot = sbase4[WVN - 1] + ucnt4[WVN - 1];
    for (int k = t; k < usedtot * 64; k += KT) pool[k] = 0xFFFFFFFFu;
    __syncthreads();
    unsigned short* inv = (unsigned short*)pool;
#pragma unroll
    for (int q = 0; q < SPT; ++q) {
        const int s = q * KT + t;
        const unsigned v = lvrk[s];
        const int lvl  = (int)(v & 0xFFu);
        const int rank = (int)(v >> 8) + lcnt[lvl * NSG + sg];
        const int cl   = rank >> 7;
        const int pos  = rank & 127;
        int wv2, wc2;
        if (serf[lvl]) { wv2 = 0; wc2 = cl; }
        else           { wv2 = cl & (WVN - 1); wc2 = cl >> 2; }
        const int pch = (int)((wvbase[lvl] >> (8 * wv2)) & 0xFFu) + wc2;
        if (pch < ucnt4[wv2]) {
            const int ipos = (sbase4[wv2] + pch) * 128 + pos;
            if (ipos < INVCAP) inv[ipos] = (unsigned short)s;
        }
    }
    __syncthreads();

    // ---- coalesced exact emission -----------------------------------------
    const uint4 padrec = { (unsigned)(PADI * 8), 0x3F800000u, 0u, (unsigned)(PADJ * 8) };
    for (int wv = 0; wv < WVN; ++wv) {
        const int npos = ucnt4[wv] * 128;
        const int ibase = sbase4[wv] * 128;
        uint4* dst = slotp + (size_t)wv * (PWC * CHUNK);
        for (int p = t; p < npos; p += KT) {
            const unsigned s = inv[ibase + p];
            uint4 r = padrec;
            if (s != 0xFFFFu) {
                const int g = gb + (int)s;
                r.x = (unsigned)(I[g] * 8);
                r.y = __builtin_bit_cast(unsigned, C[g]);
                r.z = __builtin_bit_cast(unsigned, S[g]);
                r.w = (unsigned)(J[g] * 8);
            }
            dst[p] = r;
        }
    }
}

// ---------------------------------------------------------------------------
// walk body (R18 inner loop; setprio biases CU arbitration vs GEMM waves)
// ---------------------------------------------------------------------------
__device__ void walk_body(char* smem, int pr,
                          const float* __restrict__ X, const float* __restrict__ vec,
                          const uint4* __restrict__ recs, const int* __restrict__ nlvls,
                          const unsigned* __restrict__ lvmeta_g,
                          float* __restrict__ dstbuf, int directadd) {
    float2* rw = (float2*)smem;
    unsigned* lvm = (unsigned*)(smem + (DIM + 2) * 8);
    const int tid  = threadIdx.x;
    const int wv   = tid >> 6;
    const int lane = tid & 63;
    const int rA   = pr * 2, rB = pr * 2 + 1;

    {
        const float4* xa = (const float4*)(X + (size_t)rA * DIM);
        const float4* xb = (const float4*)(X + (size_t)rB * DIM);
        for (int c4 = tid; c4 < DIM / 4; c4 += 256) {
            const float4 a = xa[c4], b = xb[c4];
            rw[c4 * 4 + 0] = make_float2(a.x, b.x);
            rw[c4 * 4 + 1] = make_float2(a.y, b.y);
            rw[c4 * 4 + 2] = make_float2(a.z, b.z);
            rw[c4 * 4 + 3] = make_float2(a.w, b.w);
        }
        if (tid < 2) rw[DIM + tid] = make_float2(0.f, 0.f);
    }

    __builtin_amdgcn_s_setprio(1);     // latency-critical path: win arbitration

    for (int slot = 0; slot < NSLOT; ++slot) {
        if (slot == NW2) {
            __syncthreads();
            const float4* v4 = (const float4*)vec;
            for (int c4 = tid; c4 < DIM / 4; c4 += 256) {
                const float4 v = v4[c4];
#pragma unroll
                for (int q = 0; q < 4; ++q) {
                    float2 tv = rw[c4 * 4 + q];
                    const float sc = (q == 0) ? v.x : (q == 1) ? v.y : (q == 2) ? v.z : v.w;
                    tv.x *= sc; tv.y *= sc;
                    rw[c4 * 4 + q] = tv;
                }
            }
        }
        if (tid < MAXR) lvm[tid] = lvmeta_g[slot * MAXR + tid];
        const int nlvl = nlvls[slot];
        __syncthreads();

        const uint4* wbase = recs + (size_t)slot * SLOTREC + (size_t)wv * (PWC * CHUNK);
        uint4 r0A = wbase[lane],       r0B = wbase[64 + lane];
        uint4 r1A = wbase[128 + lane], r1B = wbase[192 + lane];
        uint4 r2A = wbase[256 + lane], r2B = wbase[320 + lane];
        int t = 0;

        for (int lvl = 0; lvl < nlvl; ++lvl) {
            const unsigned mm = lvm[lvl];
            int n = (int)((mm >> (wv * 8)) & 0xFFu);
            if (wv == 3) n &= 0x7F;
            for (int it = 0; it < n; ++it) {
                int kc = t + 3; if (kc > PWC - 1) kc = PWC - 1;
                const uint4 mA = wbase[(size_t)kc * CHUNK + lane];
                const uint4 mB = wbase[(size_t)kc * CHUNK + 64 + lane];

                const int   ia = (int)r0A.x, ja = (int)r0A.w;
                const int   ib = (int)r0B.x, jb = (int)r0B.w;
                const float ca = bitf(r0A.y), sa = bitf(r0A.z);
                const float cb = bitf(r0B.y), sb = bitf(r0B.z);
                const float2 gai = ldrw(rw, ia), gaj = ldrw(rw, ja);
                const float2 gbi = ldrw(rw, ib), gbj = ldrw(rw, jb);

                float2 wia, wja, wib, wjb;
                wia.x = fmaf(ca, gai.x,  sa * gaj.x);
                wia.y = fmaf(ca, gai.y,  sa * gaj.y);
                wja.x = fmaf(ca, gaj.x, -sa * gai.x);
                wja.y = fmaf(ca, gaj.y, -sa * gai.y);
                wib.x = fmaf(cb, gbi.x,  sb * gbj.x);
                wib.y = fmaf(cb, gbi.y,  sb * gbj.y);
                wjb.x = fmaf(cb, gbj.x, -sb * gbi.x);
                wjb.y = fmaf(cb, gbj.y, -sb * gbi.y);
                strw(rw, ia, wia); strw(rw, ja, wja);
                strw(rw, ib, wib); strw(rw, jb, wjb);

                r0A = r1A; r0B = r1B;
                r1A = r2A; r1B = r2B;
                r2A = mA;  r2B = mB;
                ++t;
            }
            if (!(mm & 0x80000000u)) {
                __builtin_amdgcn_sched_barrier(0);
                asm volatile("s_waitcnt lgkmcnt(0)" ::: "memory");
                __builtin_amdgcn_s_barrier();
                __builtin_amdgcn_sched_barrier(0);
            }
        }
    }

    __builtin_amdgcn_s_setprio(0);

    float4* oa = (float4*)(dstbuf + (size_t)rA * DIM);
    float4* ob = (float4*)(dstbuf + (size_t)rB * DIM);
    for (int c4 = tid; c4 < DIM / 4; c4 += 256) {
        const float2 p0 = rw[c4 * 4 + 0], p1 = rw[c4 * 4 + 1];
        const float2 p2 = rw[c4 * 4 + 2], p3 = rw[c4 * 4 + 3];
        float4 ta, tb;
        if (directadd) { ta = oa[c4]; tb = ob[c4]; }
        else           { ta = (float4){0,0,0,0}; tb = (float4){0,0,0,0}; }
        ta.x += p0.x; ta.y += p1.x; ta.z += p2.x; ta.w += p3.x;
        tb.x += p0.y; tb.y += p1.y; tb.z += p2.y; tb.w += p3.y;
        oa[c4] = ta; ob[c4] = tb;
    }
}

// ---------------------------------------------------------------------------
// GEMM body (bf16, global_load_lds staging, BK=64)
// ---------------------------------------------------------------------------
__device__ void gemm_body(char* smem, int bid,
                          const short* __restrict__ Xb, const short* __restrict__ Wb,
                          const float* __restrict__ bias, float* __restrict__ out,
                          float* __restrict__ parts, int nks) {
    short* As = (short*)smem;
    short* Bs = As + 128 * 64;
    const int ks   = bid % nks;
    const int tile = bid / nks;
    const int bm   = (tile >> 5) * 128;
    const int bn   = (tile & 31) * 128;
    const int tid  = threadIdx.x;
    const int lane = tid & 63;
    const int wv   = tid >> 6;
    const int wr   = (wv >> 1) * 64;
    const int wc   = (wv & 1) * 64;
    const int fr   = lane & 15;
    const int ke   = (lane >> 4) * 8;

    f32x4 acc[4][4];
#pragma unroll
    for (int m = 0; m < 4; ++m)
#pragma unroll
        for (int n = 0; n < 4; ++n) acc[m][n] = (f32x4){0.f, 0.f, 0.f, 0.f};

    const int lrow = lane >> 3;
    const int scol = (((lane & 7) ^ (lrow & 7)) << 3);
    const short* gx = Xb + (size_t)(bm + wv * 32 + lrow) * DIM + scol;
    const short* gw = Wb + (size_t)(bn + wv * 32 + lrow) * DIM + scol;
    short* lA = As + wv * 2048;
    short* lB = Bs + wv * 2048;

    const int nkt   = (DIM / 64) / nks;
    const int kbase = ks * (DIM / nks);
    for (int kt = 0; kt < nkt; ++kt) {
        const int k0 = kbase + kt * 64;
        __syncthreads();
#pragma unroll
        for (int q = 0; q < 4; ++q) {
            gl16(gx + (size_t)(q * 8) * DIM + k0, lA + q * 512);
            gl16(gw + (size_t)(q * 8) * DIM + k0, lB + q * 512);
        }
        __syncthreads();
#pragma unroll
        for (int kk = 0; kk < 64; kk += 32) {
            const int sb = (kk + ke) >> 3;
            short8 af[4], bf[4];
#pragma unroll
            for (int m = 0; m < 4; ++m) {
                const int R = wr + m * 16 + fr;
                af[m] = *(const short8*)&As[R * 64 + ((sb ^ (R & 7)) << 3)];
            }
#pragma unroll
            for (int n = 0; n < 4; ++n) {
                const int R = wc + n * 16 + fr;
                bf[n] = *(const short8*)&Bs[R * 64 + ((sb ^ (R & 7)) << 3)];
            }
#pragma unroll
            for (int m = 0; m < 4; ++m)
#pragma unroll
                for (int n = 0; n < 4; ++n)
                    acc[m][n] = __builtin_amdgcn_mfma_f32_16x16x32_bf16(
                        __builtin_bit_cast(bf16x8, af[m]),
                        __builtin_bit_cast(bf16x8, bf[n]),
                        acc[m][n], 0, 0, 0);
        }
    }
    float* dst = ks ? (parts + (size_t)(ks - 1) * ROWS * DIM) : out;
#pragma unroll
    for (int n = 0; n < 4; ++n) {
        const int col = bn + wc + n * 16 + fr;
        const float bv = ks ? 0.f : bias[col];
#pragma unroll
        for (int m = 0; m < 4; ++m) {
            const int rbase = bm + wr + m * 16 + (lane >> 4) * 4;
#pragma unroll
            for (int r = 0; r < 4; ++r)
                dst[(size_t)(rbase + r) * DIM + col] = acc[m][n][r] + bv;
        }
    }
}

// ---------------------------------------------------------------------------
// 2) kboth: walk (blocks 0..255) + GEMM (blocks 256..) in one launch
// ---------------------------------------------------------------------------
__global__ __launch_bounds__(256) void kboth(
    const float* __restrict__ X, const float* __restrict__ vec,
    const uint4* __restrict__ recs, const int* __restrict__ nlvls,
    const unsigned* __restrict__ lvmeta_g, float* __restrict__ walkbuf,
    const short* __restrict__ Xb, const short* __restrict__ Wb,
    const float* __restrict__ bias, float* __restrict__ out,
    float* __restrict__ parts, int nks) {
    __shared__ __align__(16) char smem[SMEMB];
    if (blockIdx.x < ROWS / 2)
        walk_body(smem, blockIdx.x, X, vec, recs, nlvls, lvmeta_g, walkbuf, 0);
    else
        gemm_body(smem, blockIdx.x - ROWS / 2, Xb, Wb, bias, out, parts, nks);
}

// ---------------------------------------------------------------------------
// 3) kadd: out += walkbuf + sum(parts)
// ---------------------------------------------------------------------------
__global__ __launch_bounds__(256) void kadd(float* __restrict__ out,
                                            const float* __restrict__ walkbuf,
                                            const float* __restrict__ parts, int nparts) {
    const size_t N = (size_t)ROWS * DIM / 4;
    const size_t i0 = (size_t)blockIdx.x * 256 + threadIdx.x;
    float4* o4 = (float4*)out;
    const float4* w4 = (const float4*)walkbuf;
    const float4* p4 = (const float4*)parts;
    for (size_t i = i0; i < N; i += (size_t)gridDim.x * 256) {
        float4 t = o4[i];
        const float4 s = w4[i];
        t.x += s.x; t.y += s.y; t.z += s.z; t.w += s.w;
        for (int p = 0; p < nparts; ++p) {
            const float4 a = p4[i + (size_t)p * N];
            t.x += a.x; t.y += a.y; t.z += a.z; t.w += a.w;
        }
        o4[i] = t;
    }
}

// ---------------------------------------------------------------------------
// fallback kernels (small workspace): fp32-staging GEMM + direct-add walk
// ---------------------------------------------------------------------------
#define LDT 72
__global__ __launch_bounds__(256) void kgemm_small(const float* __restrict__ X, const float* __restrict__ W,
                                                   const float* __restrict__ bias, float* __restrict__ out) {
    __shared__ short As[64 * LDT];
    __shared__ short Bs[128 * LDT];
    const int tid  = threadIdx.x;
    const int bn   = (blockIdx.x & 31) * 128;
    const int bm   = (blockIdx.x >> 5) * 64;
    const int lane = tid & 63;
    const int wv   = tid >> 6;
    const int wr   = (wv >> 1) * 32;
    const int wc   = (wv & 1) * 64;
    const int fr   = lane & 15;
    const int ke   = (lane >> 4) * 8;

    f32x4 acc[2][4];
#pragma unroll
    for (int m = 0; m < 2; ++m)
#pragma unroll
        for (int n = 0; n < 4; ++n) acc[m][n] = (f32x4){0.f, 0.f, 0.f, 0.f};

    const int tr = tid >> 2;
    const int tc = (tid & 3) << 4;

    for (int kt = 0; kt < DIM / 64; ++kt) {
        const int k0 = kt * 64;
        float4 ra[4], rb[2][4];
        {
            const float4* ga = (const float4*)(X + (size_t)(bm + tr) * DIM + k0 + tc);
#pragma unroll
            for (int q = 0; q < 4; ++q) ra[q] = ga[q];
#pragma unroll
            for (int h = 0; h < 2; ++h) {
                const float4* gw = (const float4*)(W + (size_t)(bn + h * 64 + tr) * DIM + k0 + tc);
#pragma unroll
                for (int q = 0; q < 4; ++q) rb[h][q] = gw[q];
            }
        }
        __syncthreads();
        *(short8*)&As[tr * LDT + tc]     = pack8(ra[0], ra[1]);
        *(short8*)&As[tr * LDT + tc + 8] = pack8(ra[2], ra[3]);
#pragma unroll
        for (int h = 0; h < 2; ++h) {
            *(short8*)&Bs[(h * 64 + tr) * LDT + tc]     = pack8(rb[h][0], rb[h][1]);
            *(short8*)&Bs[(h * 64 + tr) * LDT + tc + 8] = pack8(rb[h][2], rb[h][3]);
        }
        __syncthreads();
#pragma unroll
        for (int kk = 0; kk < 64; kk += 32) {
            short8 af[2], bf[4];
#pragma unroll
            for (int m = 0; m < 2; ++m)
                af[m] = *(const short8*)&As[(wr + m * 16 + fr) * LDT + kk + ke];
#pragma unroll
            for (int n = 0; n < 4; ++n)
                bf[n] = *(const short8*)&Bs[(wc + n * 16 + fr) * LDT + kk + ke];
#pragma unroll
            for (int m = 0; m < 2; ++m)
#pragma unroll
                for (int n = 0; n < 4; ++n)
                    acc[m][n] = __builtin_amdgcn_mfma_f32_16x16x32_bf16(
                        __builtin_bit_cast(bf16x8, af[m]),
                        __builtin_bit_cast(bf16x8, bf[n]),
                        acc[m][n], 0, 0, 0);
        }
    }
#pragma unroll
    for (int n = 0; n < 4; ++n) {
        const int col = bn + wc + n * 16 + fr;
        const float bv = bias[col];
#pragma unroll
        for (int m = 0; m < 2; ++m) {
            const int rbase = bm + wr + m * 16 + (lane >> 4) * 4;
#pragma unroll
            for (int r = 0; r < 4; ++r)
                out[(size_t)(rbase + r) * DIM + col] = acc[m][n][r] + bv;
        }
    }
}

__global__ __launch_bounds__(256) void kwalk_fb(const float* __restrict__ X, const float* __restrict__ vec,
                                                const uint4* __restrict__ recs, const int* __restrict__ nlvls,
                                                const unsigned* __restrict__ lvmeta_g,
                                                float* __restrict__ out) {
    __shared__ __align__(16) char smem[SMEMB];
    walk_body(smem, blockIdx.x, X, vec, recs, nlvls, lvmeta_g, out, 1);
}

// ---------------------------------------------------------------------------
extern "C" void kernel_launch(void* const* d_in, const int* in_sizes, int n_in,
                              void* d_out, int out_size, void* d_ws, size_t ws_size,
                              hipStream_t stream) {
    const float* X    = (const float*)d_in[0];
    const float* W    = (const float*)d_in[1];
    const float* bias = (const float*)d_in[2];
    const float* vec  = (const float*)d_in[3];
    const int*   i1   = (const int*)d_in[4];
    const int*   j1   = (const int*)d_in[5];
    const float* c1   = (const float*)d_in[6];
    const float* s1   = (const float*)d_in[7];
    const int*   i2   = (const int*)d_in[8];
    const int*   j2   = (const int*)d_in[9];
    const float* c2   = (const float*)d_in[10];
    const float* s2   = (const float*)d_in[11];
    float* out = (float*)d_out;

    const size_t RD         = (size_t)ROWS * DIM * 4;            // 8 MiB
    const size_t WBB        = (size_t)DIM * DIM * 2;             // 32 MiB
    const size_t XBB        = (size_t)ROWS * DIM * 2;            // 4 MiB
    const size_t recs_bytes = (size_t)NSLOT * SLOTREC * 16;      // 9.44 MiB
    const size_t off_lvm    = recs_bytes + 1024;
    const size_t off_parts  = recs_bytes + 16384;

    // Ksplit=2: 1 walk + 1 GEMM block per CU (less walk contention than 4)
    int nks = 0;
    size_t off_wb = 0;
    {
        const size_t need2 = off_parts + 1 * RD + WBB + XBB + RD;
        if (ws_size >= need2) { nks = 2; off_wb = off_parts + 1 * RD; }
    }

    uint4*    recs   = (uint4*)d_ws;
    int*      nlvlsb = (int*)((char*)d_ws + recs_bytes);
    unsigned* lvmeta = (unsigned*)((char*)d_ws + off_lvm);
    float*    parts  = (float*)((char*)d_ws + off_parts);
    short*    wbuf   = (short*)((char*)d_ws + off_wb);
    short*    xbuf   = (short*)((char*)d_ws + off_wb + WBB);
    float*    wkbuf  = (float*)((char*)d_ws + off_wb + WBB + XBB);
    const bool bf = (nks > 0);

    hipLaunchKernelGGL(kfused, dim3(NSLOT + (bf ? (NCVW + NCVX) : 0)), dim3(KT), 0, stream,
                       i1, j1, c1, s1, i2, j2, c2, s2, recs, nlvlsb, lvmeta,
                       bf ? 1 : 0, W, X, wbuf, xbuf);
    if (bf) {
        hipLaunchKernelGGL(kboth, dim3(ROWS / 2 + 128 * nks), dim3(256), 0, stream,
                           X, vec, recs, nlvlsb, lvmeta, wkbuf,
                           xbuf, wbuf, bias, out, parts, nks);
        hipLaunchKernelGGL(kadd, dim3(512), dim3(256), 0, stream,
                           out, wkbuf, parts, nks - 1);
    } else {
        hipLaunchKernelGGL(kgemm_small, dim3(256), dim3(256), 0, stream, X, W, bias, out);
        hipLaunchKernelGGL(kwalk_fb, dim3(ROWS / 2), dim3(256), 0, stream,
                           X, vec, recs, nlvlsb, lvmeta, out);
    }
}

// Round 22
// 199.930 us; speedup vs baseline: 1.0853x; 1.0853x over previous
//
#include <hip/hip_runtime.h>

// KacLayer: out[512][4096] = x @ W^T + b  +  Kac2( vec * Kac1( x ) )
//
//  kfused: blocks 0..11: per-8192-step window scheduler (R20 election:
//          round-stamped atomicMin keys — measured faster than lazy-stamp).
//          Depth election -> per-wave chunk streams (levels <=2 chunks serial
//          on wave0, barrier elision). Exact emission via u16 inverse
//          permutation. Bit-exact reorder of commuting Givens rotations.
//          blocks 12..1163: fp32->bf16 convert of W and X into d_ws.
//  kboth : ONE launch, blocks 0..255 = walk path (4 waves / row-pair,
//          level-parallel, light barriers, s_setprio(1) hot loop), blocks
//          256..383 = GEMM path (128x128, BK=64, global_load_lds staging,
//          swizzled LDS, Ksplit=2 — measured better than 4: less walk
//          contention, GEMM tail still hidden under walk).
//  kadd  : out = gemm_out + walkbuf + partial.

#define DIM    4096
#define ROWS   512
#define NSTEPS 49152
#define WSTEPS 8192
#define NW2    (NSTEPS / WSTEPS)   // 6 windows per walk
#define NSLOT  (2 * NW2)           // 12 slots
#define NSG    16                  // rank subgroups (one per ksched wave)
#define CHUNK  128
#define WVN    4                   // walk waves per block
#define PWC    96                  // per-wave chunk capacity per slot
#define SLOTREC (WVN * PWC * CHUNK)   // 49152 records per slot
#define MAXR   96
#define PADI   4096
#define PADJ   4097
#define KT     1024                // scheduler threads
#define SPT    (WSTEPS / KT)       // 8 steps per thread
#define NCVW   1024                // W-convert blocks
#define NCVX   128                 // X-convert blocks
#define SMEMB  33664               // kboth shared bytes (walk needs 33168)
#define INVCAP ((DIM + WSTEPS) * 2)   // 24576 u16 entries = 192 chunks

typedef short  short8 __attribute__((ext_vector_type(8)));
typedef __bf16 bf16x8 __attribute__((ext_vector_type(8)));
typedef float  f32x4  __attribute__((ext_vector_type(4)));

__device__ inline short f2bf(float f) {
    unsigned u = __builtin_bit_cast(unsigned, f);
    u += 0x7FFFu + ((u >> 16) & 1u);
    return (short)(u >> 16);
}
__device__ inline short8 pack8(float4 a, float4 b) {
    short8 r;
    r[0] = f2bf(a.x); r[1] = f2bf(a.y); r[2] = f2bf(a.z); r[3] = f2bf(a.w);
    r[4] = f2bf(b.x); r[5] = f2bf(b.y); r[6] = f2bf(b.z); r[7] = f2bf(b.w);
    return r;
}
__device__ inline float bitf(unsigned u) { return __builtin_bit_cast(float, u); }
__device__ inline float2 ldrw(const float2* rw, int boff) {
    return *(const float2*)((const char*)rw + boff);
}
__device__ inline void strw(float2* rw, int boff, float2 v) {
    *(float2*)((char*)rw + boff) = v;
}
__device__ inline void gl16(const short* g, short* l) {
    __builtin_amdgcn_global_load_lds((const __attribute__((address_space(1))) unsigned*)g,
                                     (__attribute__((address_space(3))) unsigned*)l, 16, 0, 0);
}

// ---------------------------------------------------------------------------
// 1) fused scheduler (blocks 0..NSLOT-1) + bf16 convert (blocks NSLOT..)
// ---------------------------------------------------------------------------
__global__ __launch_bounds__(KT) void kfused(
    const int* __restrict__ i1, const int* __restrict__ j1,
    const float* __restrict__ c1, const float* __restrict__ s1,
    const int* __restrict__ i2, const int* __restrict__ j2,
    const float* __restrict__ c2, const float* __restrict__ s2,
    uint4* __restrict__ recs, int* __restrict__ nlvls, unsigned* __restrict__ lvmeta_g,
    int doconv, const float* __restrict__ W, const float* __restrict__ X,
    short* __restrict__ wb, short* __restrict__ xb) {

    if (blockIdx.x >= NSLOT) {
        if (!doconv) return;
        const int cb = blockIdx.x - NSLOT;
        const float* src; short* dst; size_t base;
        if (cb < NCVW) { src = W; dst = wb; base = (size_t)cb * 16384; }
        else           { src = X; dst = xb; base = (size_t)(cb - NCVW) * 16384; }
        const size_t o = base + (size_t)threadIdx.x * 16;
        const float4* s4 = (const float4*)(src + o);
        const float4 a0 = s4[0], a1 = s4[1], a2 = s4[2], a3 = s4[3];
        *(short8*)(dst + o)     = pack8(a0, a1);
        *(short8*)(dst + o + 8) = pack8(a2, a3);
        return;
    }

    __shared__ unsigned pool[DIM + WSTEPS];      // 48 KB (tbl+spair; then inv)
    __shared__ unsigned lvrk[WSTEPS];            // 32 KB: rank<<8 | level
    __shared__ int lcnt[MAXR * NSG];             // 6 KB
    __shared__ unsigned lvpk[MAXR], wvbase[MAXR];
    __shared__ unsigned char serf[MAXR];
    __shared__ int nlvlsh;
    __shared__ unsigned totpk;
    __shared__ int ucnt4[WVN], sbase4[WVN];

    unsigned* tbl   = pool;
    unsigned* spair = pool + DIM;

    const int b    = blockIdx.x;
    const int walk = b / NW2;
    const int w    = b % NW2;
    const int t    = threadIdx.x;
    const int gb   = w * WSTEPS;
    const int sg   = t >> 6;

    const int*   I = walk ? i2 : i1;
    const int*   J = walk ? j2 : j1;
    const float* C = walk ? c2 : c1;
    const float* S = walk ? s2 : s1;

    uint4* slotp = recs + (size_t)b * SLOTREC;

    for (int s = t; s < WSTEPS; s += KT)
        spair[s] = (unsigned)I[gb + s] | ((unsigned)J[gb + s] << 16);
    for (int k = t; k < DIM; k += KT) tbl[k] = 0xFFFFFFFFu;
    for (int k = t; k < MAXR * NSG; k += KT) lcnt[k] = 0;
    if (t < MAXR) serf[t] = 0;
    if (t == 0) nlvlsh = 1;
    __syncthreads();

    // ---- election: round-stamped keys; 2 barriers/round; level = depth ----
    unsigned pmask = (1u << SPT) - 1u;
    for (int rr = 0; rr < MAXR; ++rr) {
        const unsigned rk = (unsigned)(MAXR - 1 - rr) << 13;
#pragma unroll
        for (int q = 0; q < SPT; ++q)
            if (pmask & (1u << q)) {
                const int s = q * KT + t;
                const unsigned sp = spair[s];
                const unsigned key = rk | (unsigned)s;
                atomicMin(&tbl[sp & 0xFFFFu], key);
                atomicMin(&tbl[sp >> 16], key);
            }
        __syncthreads();
#pragma unroll
        for (int q = 0; q < SPT; ++q)
            if (pmask & (1u << q)) {
                const int s = q * KT + t;
                const unsigned sp = spair[s];
                const unsigned key = rk | (unsigned)s;
                if (tbl[sp & 0xFFFFu] == key && tbl[sp >> 16] == key) {
                    const int rank = atomicAdd(&lcnt[rr * NSG + sg], 1);
                    lvrk[s] = ((unsigned)rank << 8) | (unsigned)rr;
                    pmask &= ~(1u << q);
                }
            }
        const int np = __syncthreads_count(pmask != 0);
        if (np == 0) break;
    }
#pragma unroll
    for (int q = 0; q < SPT; ++q)
        if (pmask & (1u << q)) {       // statistically unreachable
            const int s = q * KT + t;
            const int rank = atomicAdd(&lcnt[(MAXR - 1) * NSG + sg], 1);
            lvrk[s] = ((unsigned)rank << 8) | (unsigned)(MAXR - 1);
        }
    __syncthreads();

    // ---- layout -----------------------------------------------------------
    if (t < MAXR) {
        int run = 0;
        for (int g = 0; g < NSG; ++g) {
            const int v = lcnt[t * NSG + g];
            lcnt[t * NSG + g] = run;
            run += v;
        }
        const int nch = (run + 127) >> 7;
        unsigned pk = 0;
        if (run > 0 && nch <= 2) { serf[t] = 1; pk = (unsigned)nch; }
        else {
#pragma unroll
            for (int wv = 0; wv < WVN; ++wv)
                pk |= (unsigned)((nch + (WVN - 1 - wv)) >> 2) << (8 * wv);
        }
        lvpk[t] = pk;
        if (run > 0) atomicMax(&nlvlsh, t + 1);
    }
    __syncthreads();
    if (t < 64) {
        const int l = t;
        const unsigned w1 = lvpk[l];
        unsigned x1 = w1;
        for (int off = 1; off < 64; off <<= 1) {
            const unsigned v = (unsigned)__shfl_up((int)x1, off);
            if (l >= off) x1 += v;
        }
        wvbase[l] = x1 - w1;
        const unsigned seg1 = (unsigned)__shfl((int)x1, 63);
        const int l2 = 64 + (l & 31);
        const unsigned w2 = lvpk[l2];
        unsigned x2 = w2;
        for (int off = 1; off < 32; off <<= 1) {
            const unsigned v = (unsigned)__shfl_up((int)x2, off);
            if ((l & 31) >= off) x2 += v;
        }
        if (l < 32) wvbase[l2] = seg1 + x2 - w2;
        if (l == 31) totpk = seg1 + x2;
    }
    __syncthreads();
    if (t < WVN) {
        int u = (int)((totpk >> (8 * t)) & 0xFFu);
        ucnt4[t] = (u > PWC) ? PWC : u;
    }
    if (t < MAXR - 1) {
        if (serf[t] && serf[t + 1]) lvpk[t] |= 0x80000000u;
    }
    __syncthreads();
    if (t == 0) {
        sbase4[0] = 0;
        for (int v = 1; v < WVN; ++v) sbase4[v] = sbase4[v - 1] + ucnt4[v - 1];
        nlvls[b] = nlvlsh;
    }
    if (t < MAXR) lvmeta_g[b * MAXR + t] = lvpk[t];
    __syncthreads();

    // ---- inv table over used positions (reuses pool) ----------------------
    const int usedtot = sbase4[WVN - 1] + ucnt4[WVN - 1];
    for (int k = t; k < usedtot * 64; k += KT) pool[k] = 0xFFFFFFFFu;
    __syncthreads();
    unsigned short* inv = (unsigned short*)pool;
#pragma unroll
    for (int q = 0; q < SPT; ++q) {
        const int s = q * KT + t;
        const unsigned v = lvrk[s];
        const int lvl  = (int)(v & 0xFFu);
        const int rank = (int)(v >> 8) + lcnt[lvl * NSG + sg];
        const int cl   = rank >> 7;
        const int pos  = rank & 127;
        int wv2, wc2;
        if (serf[lvl]) { wv2 = 0; wc2 = cl; }
        else           { wv2 = cl & (WVN - 1); wc2 = cl >> 2; }
        const int pch = (int)((wvbase[lvl] >> (8 * wv2)) & 0xFFu) + wc2;
        if (pch < ucnt4[wv2]) {
            const int ipos = (sbase4[wv2] + pch) * 128 + pos;
            if (ipos < INVCAP) inv[ipos] = (unsigned short)s;
        }
    }
    __syncthreads();

    // ---- coalesced exact emission -----------------------------------------
    const uint4 padrec = { (unsigned)(PADI * 8), 0x3F800000u, 0u, (unsigned)(PADJ * 8) };
    for (int wv = 0; wv < WVN; ++wv) {
        const int npos = ucnt4[wv] * 128;
        const int ibase = sbase4[wv] * 128;
        uint4* dst = slotp + (size_t)wv * (PWC * CHUNK);
        for (int p = t; p < npos; p += KT) {
            const unsigned s = inv[ibase + p];
            uint4 r = padrec;
            if (s != 0xFFFFu) {
                const int g = gb + (int)s;
                r.x = (unsigned)(I[g] * 8);
                r.y = __builtin_bit_cast(unsigned, C[g]);
                r.z = __builtin_bit_cast(unsigned, S[g]);
                r.w = (unsigned)(J[g] * 8);
            }
            dst[p] = r;
        }
    }
}

// ---------------------------------------------------------------------------
// walk body (R18 inner loop; setprio biases CU arbitration vs GEMM waves)
// ---------------------------------------------------------------------------
__device__ void walk_body(char* smem, int pr,
                          const float* __restrict__ X, const float* __restrict__ vec,
                          const uint4* __restrict__ recs, const int* __restrict__ nlvls,
                          const unsigned* __restrict__ lvmeta_g,
                          float* __restrict__ dstbuf, int directadd) {
    float2* rw = (float2*)smem;
    unsigned* lvm = (unsigned*)(smem + (DIM + 2) * 8);
    const int tid  = threadIdx.x;
    const int wv   = tid >> 6;
    const int lane = tid & 63;
    const int rA   = pr * 2, rB = pr * 2 + 1;

    {
        const float4* xa = (const float4*)(X + (size_t)rA * DIM);
        const float4* xb = (const float4*)(X + (size_t)rB * DIM);
        for (int c4 = tid; c4 < DIM / 4; c4 += 256) {
            const float4 a = xa[c4], b = xb[c4];
            rw[c4 * 4 + 0] = make_float2(a.x, b.x);
            rw[c4 * 4 + 1] = make_float2(a.y, b.y);
            rw[c4 * 4 + 2] = make_float2(a.z, b.z);
            rw[c4 * 4 + 3] = make_float2(a.w, b.w);
        }
        if (tid < 2) rw[DIM + tid] = make_float2(0.f, 0.f);
    }

    __builtin_amdgcn_s_setprio(1);     // latency-critical path: win arbitration

    for (int slot = 0; slot < NSLOT; ++slot) {
        if (slot == NW2) {
            __syncthreads();
            const float4* v4 = (const float4*)vec;
            for (int c4 = tid; c4 < DIM / 4; c4 += 256) {
                const float4 v = v4[c4];
#pragma unroll
                for (int q = 0; q < 4; ++q) {
                    float2 tv = rw[c4 * 4 + q];
                    const float sc = (q == 0) ? v.x : (q == 1) ? v.y : (q == 2) ? v.z : v.w;
                    tv.x *= sc; tv.y *= sc;
                    rw[c4 * 4 + q] = tv;
                }
            }
        }
        if (tid < MAXR) lvm[tid] = lvmeta_g[slot * MAXR + tid];
        const int nlvl = nlvls[slot];
        __syncthreads();

        const uint4* wbase = recs + (size_t)slot * SLOTREC + (size_t)wv * (PWC * CHUNK);
        uint4 r0A = wbase[lane],       r0B = wbase[64 + lane];
        uint4 r1A = wbase[128 + lane], r1B = wbase[192 + lane];
        uint4 r2A = wbase[256 + lane], r2B = wbase[320 + lane];
        int t = 0;

        for (int lvl = 0; lvl < nlvl; ++lvl) {
            const unsigned mm = lvm[lvl];
            int n = (int)((mm >> (wv * 8)) & 0xFFu);
            if (wv == 3) n &= 0x7F;
            for (int it = 0; it < n; ++it) {
                int kc = t + 3; if (kc > PWC - 1) kc = PWC - 1;
                const uint4 mA = wbase[(size_t)kc * CHUNK + lane];
                const uint4 mB = wbase[(size_t)kc * CHUNK + 64 + lane];

                const int   ia = (int)r0A.x, ja = (int)r0A.w;
                const int   ib = (int)r0B.x, jb = (int)r0B.w;
                const float ca = bitf(r0A.y), sa = bitf(r0A.z);
                const float cb = bitf(r0B.y), sb = bitf(r0B.z);
                const float2 gai = ldrw(rw, ia), gaj = ldrw(rw, ja);
                const float2 gbi = ldrw(rw, ib), gbj = ldrw(rw, jb);

                float2 wia, wja, wib, wjb;
                wia.x = fmaf(ca, gai.x,  sa * gaj.x);
                wia.y = fmaf(ca, gai.y,  sa * gaj.y);
                wja.x = fmaf(ca, gaj.x, -sa * gai.x);
                wja.y = fmaf(ca, gaj.y, -sa * gai.y);
                wib.x = fmaf(cb, gbi.x,  sb * gbj.x);
                wib.y = fmaf(cb, gbi.y,  sb * gbj.y);
                wjb.x = fmaf(cb, gbj.x, -sb * gbi.x);
                wjb.y = fmaf(cb, gbj.y, -sb * gbi.y);
                strw(rw, ia, wia); strw(rw, ja, wja);
                strw(rw, ib, wib); strw(rw, jb, wjb);

                r0A = r1A; r0B = r1B;
                r1A = r2A; r1B = r2B;
                r2A = mA;  r2B = mB;
                ++t;
            }
            if (!(mm & 0x80000000u)) {
                __builtin_amdgcn_sched_barrier(0);
                asm volatile("s_waitcnt lgkmcnt(0)" ::: "memory");
                __builtin_amdgcn_s_barrier();
                __builtin_amdgcn_sched_barrier(0);
            }
        }
    }

    __builtin_amdgcn_s_setprio(0);

    float4* oa = (float4*)(dstbuf + (size_t)rA * DIM);
    float4* ob = (float4*)(dstbuf + (size_t)rB * DIM);
    for (int c4 = tid; c4 < DIM / 4; c4 += 256) {
        const float2 p0 = rw[c4 * 4 + 0], p1 = rw[c4 * 4 + 1];
        const float2 p2 = rw[c4 * 4 + 2], p3 = rw[c4 * 4 + 3];
        float4 ta, tb;
        if (directadd) { ta = oa[c4]; tb = ob[c4]; }
        else           { ta = (float4){0,0,0,0}; tb = (float4){0,0,0,0}; }
        ta.x += p0.x; ta.y += p1.x; ta.z += p2.x; ta.w += p3.x;
        tb.x += p0.y; tb.y += p1.y; tb.z += p2.y; tb.w += p3.y;
        oa[c4] = ta; ob[c4] = tb;
    }
}

// ---------------------------------------------------------------------------
// GEMM body (bf16, global_load_lds staging, BK=64)
// ---------------------------------------------------------------------------
__device__ void gemm_body(char* smem, int bid,
                          const short* __restrict__ Xb, const short* __restrict__ Wb,
                          const float* __restrict__ bias, float* __restrict__ out,
                          float* __restrict__ parts, int nks) {
    short* As = (short*)smem;
    short* Bs = As + 128 * 64;
    const int ks   = bid % nks;
    const int tile = bid / nks;
    const int bm   = (tile >> 5) * 128;
    const int bn   = (tile & 31) * 128;
    const int tid  = threadIdx.x;
    const int lane = tid & 63;
    const int wv   = tid >> 6;
    const int wr   = (wv >> 1) * 64;
    const int wc   = (wv & 1) * 64;
    const int fr   = lane & 15;
    const int ke   = (lane >> 4) * 8;

    f32x4 acc[4][4];
#pragma unroll
    for (int m = 0; m < 4; ++m)
#pragma unroll
        for (int n = 0; n < 4; ++n) acc[m][n] = (f32x4){0.f, 0.f, 0.f, 0.f};

    const int lrow = lane >> 3;
    const int scol = (((lane & 7) ^ (lrow & 7)) << 3);
    const short* gx = Xb + (size_t)(bm + wv * 32 + lrow) * DIM + scol;
    const short* gw = Wb + (size_t)(bn + wv * 32 + lrow) * DIM + scol;
    short* lA = As + wv * 2048;
    short* lB = Bs + wv * 2048;

    const int nkt   = (DIM / 64) / nks;
    const int kbase = ks * (DIM / nks);
    for (int kt = 0; kt < nkt; ++kt) {
        const int k0 = kbase + kt * 64;
        __syncthreads();
#pragma unroll
        for (int q = 0; q < 4; ++q) {
            gl16(gx + (size_t)(q * 8) * DIM + k0, lA + q * 512);
            gl16(gw + (size_t)(q * 8) * DIM + k0, lB + q * 512);
        }
        __syncthreads();
#pragma unroll
        for (int kk = 0; kk < 64; kk += 32) {
            const int sb = (kk + ke) >> 3;
            short8 af[4], bf[4];
#pragma unroll
            for (int m = 0; m < 4; ++m) {
                const int R = wr + m * 16 + fr;
                af[m] = *(const short8*)&As[R * 64 + ((sb ^ (R & 7)) << 3)];
            }
#pragma unroll
            for (int n = 0; n < 4; ++n) {
                const int R = wc + n * 16 + fr;
                bf[n] = *(const short8*)&Bs[R * 64 + ((sb ^ (R & 7)) << 3)];
            }
#pragma unroll
            for (int m = 0; m < 4; ++m)
#pragma unroll
                for (int n = 0; n < 4; ++n)
                    acc[m][n] = __builtin_amdgcn_mfma_f32_16x16x32_bf16(
                        __builtin_bit_cast(bf16x8, af[m]),
                        __builtin_bit_cast(bf16x8, bf[n]),
                        acc[m][n], 0, 0, 0);
        }
    }
    float* dst = ks ? (parts + (size_t)(ks - 1) * ROWS * DIM) : out;
#pragma unroll
    for (int n = 0; n < 4; ++n) {
        const int col = bn + wc + n * 16 + fr;
        const float bv = ks ? 0.f : bias[col];
#pragma unroll
        for (int m = 0; m < 4; ++m) {
            const int rbase = bm + wr + m * 16 + (lane >> 4) * 4;
#pragma unroll
            for (int r = 0; r < 4; ++r)
                dst[(size_t)(rbase + r) * DIM + col] = acc[m][n][r] + bv;
        }
    }
}

// ---------------------------------------------------------------------------
// 2) kboth: walk (blocks 0..255) + GEMM (blocks 256..) in one launch
// ---------------------------------------------------------------------------
__global__ __launch_bounds__(256) void kboth(
    const float* __restrict__ X, const float* __restrict__ vec,
    const uint4* __restrict__ recs, const int* __restrict__ nlvls,
    const unsigned* __restrict__ lvmeta_g, float* __restrict__ walkbuf,
    const short* __restrict__ Xb, const short* __restrict__ Wb,
    const float* __restrict__ bias, float* __restrict__ out,
    float* __restrict__ parts, int nks) {
    __shared__ __align__(16) char smem[SMEMB];
    if (blockIdx.x < ROWS / 2)
        walk_body(smem, blockIdx.x, X, vec, recs, nlvls, lvmeta_g, walkbuf, 0);
    else
        gemm_body(smem, blockIdx.x - ROWS / 2, Xb, Wb, bias, out, parts, nks);
}

// ---------------------------------------------------------------------------
// 3) kadd: out += walkbuf + sum(parts)
// ---------------------------------------------------------------------------
__global__ __launch_bounds__(256) void kadd(float* __restrict__ out,
                                            const float* __restrict__ walkbuf,
                                            const float* __restrict__ parts, int nparts) {
    const size_t N = (size_t)ROWS * DIM / 4;
    const size_t i0 = (size_t)blockIdx.x * 256 + threadIdx.x;
    float4* o4 = (float4*)out;
    const float4* w4 = (const float4*)walkbuf;
    const float4* p4 = (const float4*)parts;
    for (size_t i = i0; i < N; i += (size_t)gridDim.x * 256) {
        float4 t = o4[i];
        const float4 s = w4[i];
        t.x += s.x; t.y += s.y; t.z += s.z; t.w += s.w;
        for (int p = 0; p < nparts; ++p) {
            const float4 a = p4[i + (size_t)p * N];
            t.x += a.x; t.y += a.y; t.z += a.z; t.w += a.w;
        }
        o4[i] = t;
    }
}

// ---------------------------------------------------------------------------
// fallback kernels (small workspace): fp32-staging GEMM + direct-add walk
// ---------------------------------------------------------------------------
#define LDT 72
__global__ __launch_bounds__(256) void kgemm_small(const float* __restrict__ X, const float* __restrict__ W,
                                                   const float* __restrict__ bias, float* __restrict__ out) {
    __shared__ short As[64 * LDT];
    __shared__ short Bs[128 * LDT];
    const int tid  = threadIdx.x;
    const int bn   = (blockIdx.x & 31) * 128;
    const int bm   = (blockIdx.x >> 5) * 64;
    const int lane = tid & 63;
    const int wv   = tid >> 6;
    const int wr   = (wv >> 1) * 32;
    const int wc   = (wv & 1) * 64;
    const int fr   = lane & 15;
    const int ke   = (lane >> 4) * 8;

    f32x4 acc[2][4];
#pragma unroll
    for (int m = 0; m < 2; ++m)
#pragma unroll
        for (int n = 0; n < 4; ++n) acc[m][n] = (f32x4){0.f, 0.f, 0.f, 0.f};

    const int tr = tid >> 2;
    const int tc = (tid & 3) << 4;

    for (int kt = 0; kt < DIM / 64; ++kt) {
        const int k0 = kt * 64;
        float4 ra[4], rb[2][4];
        {
            const float4* ga = (const float4*)(X + (size_t)(bm + tr) * DIM + k0 + tc);
#pragma unroll
            for (int q = 0; q < 4; ++q) ra[q] = ga[q];
#pragma unroll
            for (int h = 0; h < 2; ++h) {
                const float4* gw = (const float4*)(W + (size_t)(bn + h * 64 + tr) * DIM + k0 + tc);
#pragma unroll
                for (int q = 0; q < 4; ++q) rb[h][q] = gw[q];
            }
        }
        __syncthreads();
        *(short8*)&As[tr * LDT + tc]     = pack8(ra[0], ra[1]);
        *(short8*)&As[tr * LDT + tc + 8] = pack8(ra[2], ra[3]);
#pragma unroll
        for (int h = 0; h < 2; ++h) {
            *(short8*)&Bs[(h * 64 + tr) * LDT + tc]     = pack8(rb[h][0], rb[h][1]);
            *(short8*)&Bs[(h * 64 + tr) * LDT + tc + 8] = pack8(rb[h][2], rb[h][3]);
        }
        __syncthreads();
#pragma unroll
        for (int kk = 0; kk < 64; kk += 32) {
            short8 af[2], bf[4];
#pragma unroll
            for (int m = 0; m < 2; ++m)
                af[m] = *(const short8*)&As[(wr + m * 16 + fr) * LDT + kk + ke];
#pragma unroll
            for (int n = 0; n < 4; ++n)
                bf[n] = *(const short8*)&Bs[(wc + n * 16 + fr) * LDT + kk + ke];
#pragma unroll
            for (int m = 0; m < 2; ++m)
#pragma unroll
                for (int n = 0; n < 4; ++n)
                    acc[m][n] = __builtin_amdgcn_mfma_f32_16x16x32_bf16(
                        __builtin_bit_cast(bf16x8, af[m]),
                        __builtin_bit_cast(bf16x8, bf[n]),
                        acc[m][n], 0, 0, 0);
        }
    }
#pragma unroll
    for (int n = 0; n < 4; ++n) {
        const int col = bn + wc + n * 16 + fr;
        const float bv = bias[col];
#pragma unroll
        for (int m = 0; m < 2; ++m) {
            const int rbase = bm + wr + m * 16 + (lane >> 4) * 4;
#pragma unroll
            for (int r = 0; r < 4; ++r)
                out[(size_t)(rbase + r) * DIM + col] = acc[m][n][r] + bv;
        }
    }
}

__global__ __launch_bounds__(256) void kwalk_fb(const float* __restrict__ X, const float* __restrict__ vec,
                                                const uint4* __restrict__ recs, const int* __restrict__ nlvls,
                                                const unsigned* __restrict__ lvmeta_g,
                                                float* __restrict__ out) {
    __shared__ __align__(16) char smem[SMEMB];
    walk_body(smem, blockIdx.x, X, vec, recs, nlvls, lvmeta_g, out, 1);
}

// ---------------------------------------------------------------------------
extern "C" void kernel_launch(void* const* d_in, const int* in_sizes, int n_in,
                              void* d_out, int out_size, void* d_ws, size_t ws_size,
                              hipStream_t stream) {
    const float* X    = (const float*)d_in[0];
    const float* W    = (const float*)d_in[1];
    const float* bias = (const float*)d_in[2];
    const float* vec  = (const float*)d_in[3];
    const int*   i1   = (const int*)d_in[4];
    const int*   j1   = (const int*)d_in[5];
    const float* c1   = (const float*)d_in[6];
    const float* s1   = (const float*)d_in[7];
    const int*   i2   = (const int*)d_in[8];
    const int*   j2   = (const int*)d_in[9];
    const float* c2   = (const float*)d_in[10];
    const float* s2   = (const float*)d_in[11];
    float* out = (float*)d_out;

    const size_t RD         = (size_t)ROWS * DIM * 4;            // 8 MiB
    const size_t WBB        = (size_t)DIM * DIM * 2;             // 32 MiB
    const size_t XBB        = (size_t)ROWS * DIM * 2;            // 4 MiB
    const size_t recs_bytes = (size_t)NSLOT * SLOTREC * 16;      // 9.44 MiB
    const size_t off_lvm    = recs_bytes + 1024;
    const size_t off_parts  = recs_bytes + 16384;

    // Ksplit=2: 1 walk + 1 GEMM block per CU (less walk contention than 4)
    int nks = 0;
    size_t off_wb = 0;
    {
        const size_t need2 = off_parts + 1 * RD + WBB + XBB + RD;
        if (ws_size >= need2) { nks = 2; off_wb = off_parts + 1 * RD; }
    }

    uint4*    recs   = (uint4*)d_ws;
    int*      nlvlsb = (int*)((char*)d_ws + recs_bytes);
    unsigned* lvmeta = (unsigned*)((char*)d_ws + off_lvm);
    float*    parts  = (float*)((char*)d_ws + off_parts);
    short*    wbuf   = (short*)((char*)d_ws + off_wb);
    short*    xbuf   = (short*)((char*)d_ws + off_wb + WBB);
    float*    wkbuf  = (float*)((char*)d_ws + off_wb + WBB + XBB);
    const bool bf = (nks > 0);

    hipLaunchKernelGGL(kfused, dim3(NSLOT + (bf ? (NCVW + NCVX) : 0)), dim3(KT), 0, stream,
                       i1, j1, c1, s1, i2, j2, c2, s2, recs, nlvlsb, lvmeta,
                       bf ? 1 : 0, W, X, wbuf, xbuf);
    if (bf) {
        hipLaunchKernelGGL(kboth, dim3(ROWS / 2 + 128 * nks), dim3(256), 0, stream,
                           X, vec, recs, nlvlsb, lvmeta, wkbuf,
                           xbuf, wbuf, bias, out, parts, nks);
        hipLaunchKernelGGL(kadd, dim3(512), dim3(256), 0, stream,
                           out, wkbuf, parts, nks - 1);
    } else {
        hipLaunchKernelGGL(kgemm_small, dim3(256), dim3(256), 0, stream, X, W, bias, out);
        hipLaunchKernelGGL(kwalk_fb, dim3(ROWS / 2), dim3(256), 0, stream,
                           X, vec, recs, nlvlsb, lvmeta, out);
    }
}

// Round 23
// 186.170 us; speedup vs baseline: 1.1655x; 1.0739x over previous
//
#include <hip/hip_runtime.h>

// KacLayer: out[512][4096] = x @ W^T + b  +  Kac2( vec * Kac1( x ) )
//
//  kfused: blocks 0..23: per-4096-step window scheduler (halved windows:
//          election work ~4x lower, rounds ~15 vs 28; 24-way CU parallel).
//          Round-stamped atomicMin election -> depth levels; per-wave chunk
//          streams (levels <=2 chunks serial on wave0, barrier elision).
//          Exact emission via u16 inverse permutation. Bit-exact reorder.
//          blocks 24..1175: fp32->bf16 convert of W and X into d_ws.
//  kboth : ONE launch, blocks 0..255 = walk path (4 waves / row-pair,
//          level-parallel, light barriers, s_setprio(1)), blocks 256..383 =
//          GEMM path (128x128, BK=64, global_load_lds staging, swizzled LDS,
//          Ksplit=2).
//  kadd  : out = gemm_out + walkbuf + partial.

#define DIM    4096
#define ROWS   512
#define NSTEPS 49152
#define WSTEPS 4096
#define NW2    (NSTEPS / WSTEPS)   // 12 windows per walk
#define NSLOT  (2 * NW2)           // 24 slots
#define NSG    16                  // rank subgroups (one per ksched wave)
#define CHUNK  128
#define WVN    4                   // walk waves per block
#define PWC    96                  // per-wave chunk capacity per slot
#define SLOTREC (WVN * PWC * CHUNK)   // 49152 records per slot
#define MAXR   64
#define PADI   4096
#define PADJ   4097
#define KT     1024                // scheduler threads
#define SPT    (WSTEPS / KT)       // 4 steps per thread
#define NCVW   1024                // W-convert blocks
#define NCVX   128                 // X-convert blocks
#define SMEMB  33664               // kboth shared bytes (walk needs 33032)
#define INVCAP ((DIM + WSTEPS) * 2)   // 16384 u16 entries = 128 chunks

typedef short  short8 __attribute__((ext_vector_type(8)));
typedef __bf16 bf16x8 __attribute__((ext_vector_type(8)));
typedef float  f32x4  __attribute__((ext_vector_type(4)));

__device__ inline short f2bf(float f) {
    unsigned u = __builtin_bit_cast(unsigned, f);
    u += 0x7FFFu + ((u >> 16) & 1u);
    return (short)(u >> 16);
}
__device__ inline short8 pack8(float4 a, float4 b) {
    short8 r;
    r[0] = f2bf(a.x); r[1] = f2bf(a.y); r[2] = f2bf(a.z); r[3] = f2bf(a.w);
    r[4] = f2bf(b.x); r[5] = f2bf(b.y); r[6] = f2bf(b.z); r[7] = f2bf(b.w);
    return r;
}
__device__ inline float bitf(unsigned u) { return __builtin_bit_cast(float, u); }
__device__ inline float2 ldrw(const float2* rw, int boff) {
    return *(const float2*)((const char*)rw + boff);
}
__device__ inline void strw(float2* rw, int boff, float2 v) {
    *(float2*)((char*)rw + boff) = v;
}
__device__ inline void gl16(const short* g, short* l) {
    __builtin_amdgcn_global_load_lds((const __attribute__((address_space(1))) unsigned*)g,
                                     (__attribute__((address_space(3))) unsigned*)l, 16, 0, 0);
}

// ---------------------------------------------------------------------------
// 1) fused scheduler (blocks 0..NSLOT-1) + bf16 convert (blocks NSLOT..)
// ---------------------------------------------------------------------------
__global__ __launch_bounds__(KT) void kfused(
    const int* __restrict__ i1, const int* __restrict__ j1,
    const float* __restrict__ c1, const float* __restrict__ s1,
    const int* __restrict__ i2, const int* __restrict__ j2,
    const float* __restrict__ c2, const float* __restrict__ s2,
    uint4* __restrict__ recs, int* __restrict__ nlvls, unsigned* __restrict__ lvmeta_g,
    int doconv, const float* __restrict__ W, const float* __restrict__ X,
    short* __restrict__ wb, short* __restrict__ xb) {

    if (blockIdx.x >= NSLOT) {
        if (!doconv) return;
        const int cb = blockIdx.x - NSLOT;
        const float* src; short* dst; size_t base;
        if (cb < NCVW) { src = W; dst = wb; base = (size_t)cb * 16384; }
        else           { src = X; dst = xb; base = (size_t)(cb - NCVW) * 16384; }
        const size_t o = base + (size_t)threadIdx.x * 16;
        const float4* s4 = (const float4*)(src + o);
        const float4 a0 = s4[0], a1 = s4[1], a2 = s4[2], a3 = s4[3];
        *(short8*)(dst + o)     = pack8(a0, a1);
        *(short8*)(dst + o + 8) = pack8(a2, a3);
        return;
    }

    __shared__ unsigned pool[DIM + WSTEPS];      // 32 KB (tbl+spair; then inv)
    __shared__ unsigned lvrk[WSTEPS];            // 16 KB: rank<<8 | level
    __shared__ int lcnt[MAXR * NSG];             // 4 KB
    __shared__ unsigned lvpk[MAXR], wvbase[MAXR];
    __shared__ unsigned char serf[MAXR];
    __shared__ int nlvlsh;
    __shared__ unsigned totpk;
    __shared__ int ucnt4[WVN], sbase4[WVN];

    unsigned* tbl   = pool;
    unsigned* spair = pool + DIM;

    const int b    = blockIdx.x;
    const int walk = b / NW2;
    const int w    = b % NW2;
    const int t    = threadIdx.x;
    const int gb   = w * WSTEPS;
    const int sg   = t >> 6;

    const int*   I = walk ? i2 : i1;
    const int*   J = walk ? j2 : j1;
    const float* C = walk ? c2 : c1;
    const float* S = walk ? s2 : s1;

    uint4* slotp = recs + (size_t)b * SLOTREC;

    for (int s = t; s < WSTEPS; s += KT)
        spair[s] = (unsigned)I[gb + s] | ((unsigned)J[gb + s] << 16);
    for (int k = t; k < DIM; k += KT) tbl[k] = 0xFFFFFFFFu;
    for (int k = t; k < MAXR * NSG; k += KT) lcnt[k] = 0;
    if (t < MAXR) serf[t] = 0;
    if (t == 0) nlvlsh = 1;
    __syncthreads();

    // ---- election: round-stamped keys; 2 barriers/round; level = depth ----
    unsigned pmask = (1u << SPT) - 1u;
    for (int rr = 0; rr < MAXR; ++rr) {
        const unsigned rk = (unsigned)(MAXR - 1 - rr) << 13;
#pragma unroll
        for (int q = 0; q < SPT; ++q)
            if (pmask & (1u << q)) {
                const int s = q * KT + t;
                const unsigned sp = spair[s];
                const unsigned key = rk | (unsigned)s;
                atomicMin(&tbl[sp & 0xFFFFu], key);
                atomicMin(&tbl[sp >> 16], key);
            }
        __syncthreads();
#pragma unroll
        for (int q = 0; q < SPT; ++q)
            if (pmask & (1u << q)) {
                const int s = q * KT + t;
                const unsigned sp = spair[s];
                const unsigned key = rk | (unsigned)s;
                if (tbl[sp & 0xFFFFu] == key && tbl[sp >> 16] == key) {
                    const int rank = atomicAdd(&lcnt[rr * NSG + sg], 1);
                    lvrk[s] = ((unsigned)rank << 8) | (unsigned)rr;
                    pmask &= ~(1u << q);
                }
            }
        const int np = __syncthreads_count(pmask != 0);
        if (np == 0) break;
    }
#pragma unroll
    for (int q = 0; q < SPT; ++q)
        if (pmask & (1u << q)) {       // statistically unreachable
            const int s = q * KT + t;
            const int rank = atomicAdd(&lcnt[(MAXR - 1) * NSG + sg], 1);
            lvrk[s] = ((unsigned)rank << 8) | (unsigned)(MAXR - 1);
        }
    __syncthreads();

    // ---- layout -----------------------------------------------------------
    if (t < MAXR) {
        int run = 0;
        for (int g = 0; g < NSG; ++g) {
            const int v = lcnt[t * NSG + g];
            lcnt[t * NSG + g] = run;
            run += v;
        }
        const int nch = (run + 127) >> 7;
        unsigned pk = 0;
        if (run > 0 && nch <= 2) { serf[t] = 1; pk = (unsigned)nch; }
        else {
#pragma unroll
            for (int wv = 0; wv < WVN; ++wv)
                pk |= (unsigned)((nch + (WVN - 1 - wv)) >> 2) << (8 * wv);
        }
        lvpk[t] = pk;
        if (run > 0) atomicMax(&nlvlsh, t + 1);
    }
    __syncthreads();
    // packed-u8 exclusive prefix over 64 levels (single wave scan)
    if (t < 64) {
        const int l = t;
        const unsigned w1 = lvpk[l];
        unsigned x1 = w1;
        for (int off = 1; off < 64; off <<= 1) {
            const unsigned v = (unsigned)__shfl_up((int)x1, off);
            if (l >= off) x1 += v;
        }
        wvbase[l] = x1 - w1;
        if (l == 63) totpk = x1;
    }
    __syncthreads();
    if (t < WVN) {
        int u = (int)((totpk >> (8 * t)) & 0xFFu);
        ucnt4[t] = (u > PWC) ? PWC : u;
    }
    if (t < MAXR - 1) {
        if (serf[t] && serf[t + 1]) lvpk[t] |= 0x80000000u;
    }
    __syncthreads();
    if (t == 0) {
        sbase4[0] = 0;
        for (int v = 1; v < WVN; ++v) sbase4[v] = sbase4[v - 1] + ucnt4[v - 1];
        nlvls[b] = nlvlsh;
    }
    if (t < MAXR) lvmeta_g[b * MAXR + t] = lvpk[t];
    __syncthreads();

    // ---- inv table over used positions (reuses pool) ----------------------
    const int usedtot = sbase4[WVN - 1] + ucnt4[WVN - 1];
    for (int k = t; k < usedtot * 64; k += KT) pool[k] = 0xFFFFFFFFu;
    __syncthreads();
    unsigned short* inv = (unsigned short*)pool;
#pragma unroll
    for (int q = 0; q < SPT; ++q) {
        const int s = q * KT + t;
        const unsigned v = lvrk[s];
        const int lvl  = (int)(v & 0xFFu);
        const int rank = (int)(v >> 8) + lcnt[lvl * NSG + sg];
        const int cl   = rank >> 7;
        const int pos  = rank & 127;
        int wv2, wc2;
        if (serf[lvl]) { wv2 = 0; wc2 = cl; }
        else           { wv2 = cl & (WVN - 1); wc2 = cl >> 2; }
        const int pch = (int)((wvbase[lvl] >> (8 * wv2)) & 0xFFu) + wc2;
        if (pch < ucnt4[wv2]) {
            const int ipos = (sbase4[wv2] + pch) * 128 + pos;
            if (ipos < INVCAP) inv[ipos] = (unsigned short)s;
        }
    }
    __syncthreads();

    // ---- coalesced exact emission -----------------------------------------
    const uint4 padrec = { (unsigned)(PADI * 8), 0x3F800000u, 0u, (unsigned)(PADJ * 8) };
    for (int wv = 0; wv < WVN; ++wv) {
        const int npos = ucnt4[wv] * 128;
        const int ibase = sbase4[wv] * 128;
        uint4* dst = slotp + (size_t)wv * (PWC * CHUNK);
        for (int p = t; p < npos; p += KT) {
            const unsigned s = inv[ibase + p];
            uint4 r = padrec;
            if (s != 0xFFFFu) {
                const int g = gb + (int)s;
                r.x = (unsigned)(I[g] * 8);
                r.y = __builtin_bit_cast(unsigned, C[g]);
                r.z = __builtin_bit_cast(unsigned, S[g]);
                r.w = (unsigned)(J[g] * 8);
            }
            dst[p] = r;
        }
    }
}

// ---------------------------------------------------------------------------
// walk body (R18 inner loop; setprio biases CU arbitration vs GEMM waves)
// ---------------------------------------------------------------------------
__device__ void walk_body(char* smem, int pr,
                          const float* __restrict__ X, const float* __restrict__ vec,
                          const uint4* __restrict__ recs, const int* __restrict__ nlvls,
                          const unsigned* __restrict__ lvmeta_g,
                          float* __restrict__ dstbuf, int directadd) {
    float2* rw = (float2*)smem;
    unsigned* lvm = (unsigned*)(smem + (DIM + 2) * 8);
    const int tid  = threadIdx.x;
    const int wv   = tid >> 6;
    const int lane = tid & 63;
    const int rA   = pr * 2, rB = pr * 2 + 1;

    {
        const float4* xa = (const float4*)(X + (size_t)rA * DIM);
        const float4* xb = (const float4*)(X + (size_t)rB * DIM);
        for (int c4 = tid; c4 < DIM / 4; c4 += 256) {
            const float4 a = xa[c4], b = xb[c4];
            rw[c4 * 4 + 0] = make_float2(a.x, b.x);
            rw[c4 * 4 + 1] = make_float2(a.y, b.y);
            rw[c4 * 4 + 2] = make_float2(a.z, b.z);
            rw[c4 * 4 + 3] = make_float2(a.w, b.w);
        }
        if (tid < 2) rw[DIM + tid] = make_float2(0.f, 0.f);
    }

    __builtin_amdgcn_s_setprio(1);     // latency-critical path: win arbitration

    for (int slot = 0; slot < NSLOT; ++slot) {
        if (slot == NW2) {
            __syncthreads();
            const float4* v4 = (const float4*)vec;
            for (int c4 = tid; c4 < DIM / 4; c4 += 256) {
                const float4 v = v4[c4];
#pragma unroll
                for (int q = 0; q < 4; ++q) {
                    float2 tv = rw[c4 * 4 + q];
                    const float sc = (q == 0) ? v.x : (q == 1) ? v.y : (q == 2) ? v.z : v.w;
                    tv.x *= sc; tv.y *= sc;
                    rw[c4 * 4 + q] = tv;
                }
            }
        }
        if (tid < MAXR) lvm[tid] = lvmeta_g[slot * MAXR + tid];
        const int nlvl = nlvls[slot];
        __syncthreads();

        const uint4* wbase = recs + (size_t)slot * SLOTREC + (size_t)wv * (PWC * CHUNK);
        uint4 r0A = wbase[lane],       r0B = wbase[64 + lane];
        uint4 r1A = wbase[128 + lane], r1B = wbase[192 + lane];
        uint4 r2A = wbase[256 + lane], r2B = wbase[320 + lane];
        int t = 0;

        for (int lvl = 0; lvl < nlvl; ++lvl) {
            const unsigned mm = lvm[lvl];
            int n = (int)((mm >> (wv * 8)) & 0xFFu);
            if (wv == 3) n &= 0x7F;
            for (int it = 0; it < n; ++it) {
                int kc = t + 3; if (kc > PWC - 1) kc = PWC - 1;
                const uint4 mA = wbase[(size_t)kc * CHUNK + lane];
                const uint4 mB = wbase[(size_t)kc * CHUNK + 64 + lane];

                const int   ia = (int)r0A.x, ja = (int)r0A.w;
                const int   ib = (int)r0B.x, jb = (int)r0B.w;
                const float ca = bitf(r0A.y), sa = bitf(r0A.z);
                const float cb = bitf(r0B.y), sb = bitf(r0B.z);
                const float2 gai = ldrw(rw, ia), gaj = ldrw(rw, ja);
                const float2 gbi = ldrw(rw, ib), gbj = ldrw(rw, jb);

                float2 wia, wja, wib, wjb;
                wia.x = fmaf(ca, gai.x,  sa * gaj.x);
                wia.y = fmaf(ca, gai.y,  sa * gaj.y);
                wja.x = fmaf(ca, gaj.x, -sa * gai.x);
                wja.y = fmaf(ca, gaj.y, -sa * gai.y);
                wib.x = fmaf(cb, gbi.x,  sb * gbj.x);
                wib.y = fmaf(cb, gbi.y,  sb * gbj.y);
                wjb.x = fmaf(cb, gbj.x, -sb * gbi.x);
                wjb.y = fmaf(cb, gbj.y, -sb * gbi.y);
                strw(rw, ia, wia); strw(rw, ja, wja);
                strw(rw, ib, wib); strw(rw, jb, wjb);

                r0A = r1A; r0B = r1B;
                r1A = r2A; r1B = r2B;
                r2A = mA;  r2B = mB;
                ++t;
            }
            if (!(mm & 0x80000000u)) {
                __builtin_amdgcn_sched_barrier(0);
                asm volatile("s_waitcnt lgkmcnt(0)" ::: "memory");
                __builtin_amdgcn_s_barrier();
                __builtin_amdgcn_sched_barrier(0);
            }
        }
    }

    __builtin_amdgcn_s_setprio(0);

    float4* oa = (float4*)(dstbuf + (size_t)rA * DIM);
    float4* ob = (float4*)(dstbuf + (size_t)rB * DIM);
    for (int c4 = tid; c4 < DIM / 4; c4 += 256) {
        const float2 p0 = rw[c4 * 4 + 0], p1 = rw[c4 * 4 + 1];
        const float2 p2 = rw[c4 * 4 + 2], p3 = rw[c4 * 4 + 3];
        float4 ta, tb;
        if (directadd) { ta = oa[c4]; tb = ob[c4]; }
        else           { ta = (float4){0,0,0,0}; tb = (float4){0,0,0,0}; }
        ta.x += p0.x; ta.y += p1.x; ta.z += p2.x; ta.w += p3.x;
        tb.x += p0.y; tb.y += p1.y; tb.z += p2.y; tb.w += p3.y;
        oa[c4] = ta; ob[c4] = tb;
    }
}

// ---------------------------------------------------------------------------
// GEMM body (bf16, global_load_lds staging, BK=64)
// ---------------------------------------------------------------------------
__device__ void gemm_body(char* smem, int bid,
                          const short* __restrict__ Xb, const short* __restrict__ Wb,
                          const float* __restrict__ bias, float* __restrict__ out,
                          float* __restrict__ parts, int nks) {
    short* As = (short*)smem;
    short* Bs = As + 128 * 64;
    const int ks   = bid % nks;
    const int tile = bid / nks;
    const int bm   = (tile >> 5) * 128;
    const int bn   = (tile & 31) * 128;
    const int tid  = threadIdx.x;
    const int lane = tid & 63;
    const int wv   = tid >> 6;
    const int wr   = (wv >> 1) * 64;
    const int wc   = (wv & 1) * 64;
    const int fr   = lane & 15;
    const int ke   = (lane >> 4) * 8;

    f32x4 acc[4][4];
#pragma unroll
    for (int m = 0; m < 4; ++m)
#pragma unroll
        for (int n = 0; n < 4; ++n) acc[m][n] = (f32x4){0.f, 0.f, 0.f, 0.f};

    const int lrow = lane >> 3;
    const int scol = (((lane & 7) ^ (lrow & 7)) << 3);
    const short* gx = Xb + (size_t)(bm + wv * 32 + lrow) * DIM + scol;
    const short* gw = Wb + (size_t)(bn + wv * 32 + lrow) * DIM + scol;
    short* lA = As + wv * 2048;
    short* lB = Bs + wv * 2048;

    const int nkt   = (DIM / 64) / nks;
    const int kbase = ks * (DIM / nks);
    for (int kt = 0; kt < nkt; ++kt) {
        const int k0 = kbase + kt * 64;
        __syncthreads();
#pragma unroll
        for (int q = 0; q < 4; ++q) {
            gl16(gx + (size_t)(q * 8) * DIM + k0, lA + q * 512);
            gl16(gw + (size_t)(q * 8) * DIM + k0, lB + q * 512);
        }
        __syncthreads();
#pragma unroll
        for (int kk = 0; kk < 64; kk += 32) {
            const int sb = (kk + ke) >> 3;
            short8 af[4], bf[4];
#pragma unroll
            for (int m = 0; m < 4; ++m) {
                const int R = wr + m * 16 + fr;
                af[m] = *(const short8*)&As[R * 64 + ((sb ^ (R & 7)) << 3)];
            }
#pragma unroll
            for (int n = 0; n < 4; ++n) {
                const int R = wc + n * 16 + fr;
                bf[n] = *(const short8*)&Bs[R * 64 + ((sb ^ (R & 7)) << 3)];
            }
#pragma unroll
            for (int m = 0; m < 4; ++m)
#pragma unroll
                for (int n = 0; n < 4; ++n)
                    acc[m][n] = __builtin_amdgcn_mfma_f32_16x16x32_bf16(
                        __builtin_bit_cast(bf16x8, af[m]),
                        __builtin_bit_cast(bf16x8, bf[n]),
                        acc[m][n], 0, 0, 0);
        }
    }
    float* dst = ks ? (parts + (size_t)(ks - 1) * ROWS * DIM) : out;
#pragma unroll
    for (int n = 0; n < 4; ++n) {
        const int col = bn + wc + n * 16 + fr;
        const float bv = ks ? 0.f : bias[col];
#pragma unroll
        for (int m = 0; m < 4; ++m) {
            const int rbase = bm + wr + m * 16 + (lane >> 4) * 4;
#pragma unroll
            for (int r = 0; r < 4; ++r)
                dst[(size_t)(rbase + r) * DIM + col] = acc[m][n][r] + bv;
        }
    }
}

// ---------------------------------------------------------------------------
// 2) kboth: walk (blocks 0..255) + GEMM (blocks 256..) in one launch
// ---------------------------------------------------------------------------
__global__ __launch_bounds__(256) void kboth(
    const float* __restrict__ X, const float* __restrict__ vec,
    const uint4* __restrict__ recs, const int* __restrict__ nlvls,
    const unsigned* __restrict__ lvmeta_g, float* __restrict__ walkbuf,
    const short* __restrict__ Xb, const short* __restrict__ Wb,
    const float* __restrict__ bias, float* __restrict__ out,
    float* __restrict__ parts, int nks) {
    __shared__ __align__(16) char smem[SMEMB];
    if (blockIdx.x < ROWS / 2)
        walk_body(smem, blockIdx.x, X, vec, recs, nlvls, lvmeta_g, walkbuf, 0);
    else
        gemm_body(smem, blockIdx.x - ROWS / 2, Xb, Wb, bias, out, parts, nks);
}

// ---------------------------------------------------------------------------
// 3) kadd: out += walkbuf + sum(parts)
// ---------------------------------------------------------------------------
__global__ __launch_bounds__(256) void kadd(float* __restrict__ out,
                                            const float* __restrict__ walkbuf,
                                            const float* __restrict__ parts, int nparts) {
    const size_t N = (size_t)ROWS * DIM / 4;
    const size_t i0 = (size_t)blockIdx.x * 256 + threadIdx.x;
    float4* o4 = (float4*)out;
    const float4* w4 = (const float4*)walkbuf;
    const float4* p4 = (const float4*)parts;
    for (size_t i = i0; i < N; i += (size_t)gridDim.x * 256) {
        float4 t = o4[i];
        const float4 s = w4[i];
        t.x += s.x; t.y += s.y; t.z += s.z; t.w += s.w;
        for (int p = 0; p < nparts; ++p) {
            const float4 a = p4[i + (size_t)p * N];
            t.x += a.x; t.y += a.y; t.z += a.z; t.w += a.w;
        }
        o4[i] = t;
    }
}

// ---------------------------------------------------------------------------
// fallback kernels (small workspace): fp32-staging GEMM + direct-add walk
// ---------------------------------------------------------------------------
#define LDT 72
__global__ __launch_bounds__(256) void kgemm_small(const float* __restrict__ X, const float* __restrict__ W,
                                                   const float* __restrict__ bias, float* __restrict__ out) {
    __shared__ short As[64 * LDT];
    __shared__ short Bs[128 * LDT];
    const int tid  = threadIdx.x;
    const int bn   = (blockIdx.x & 31) * 128;
    const int bm   = (blockIdx.x >> 5) * 64;
    const int lane = tid & 63;
    const int wv   = tid >> 6;
    const int wr   = (wv >> 1) * 32;
    const int wc   = (wv & 1) * 64;
    const int fr   = lane & 15;
    const int ke   = (lane >> 4) * 8;

    f32x4 acc[2][4];
#pragma unroll
    for (int m = 0; m < 2; ++m)
#pragma unroll
        for (int n = 0; n < 4; ++n) acc[m][n] = (f32x4){0.f, 0.f, 0.f, 0.f};

    const int tr = tid >> 2;
    const int tc = (tid & 3) << 4;

    for (int kt = 0; kt < DIM / 64; ++kt) {
        const int k0 = kt * 64;
        float4 ra[4], rb[2][4];
        {
            const float4* ga = (const float4*)(X + (size_t)(bm + tr) * DIM + k0 + tc);
#pragma unroll
            for (int q = 0; q < 4; ++q) ra[q] = ga[q];
#pragma unroll
            for (int h = 0; h < 2; ++h) {
                const float4* gw = (const float4*)(W + (size_t)(bn + h * 64 + tr) * DIM + k0 + tc);
#pragma unroll
                for (int q = 0; q < 4; ++q) rb[h][q] = gw[q];
            }
        }
        __syncthreads();
        *(short8*)&As[tr * LDT + tc]     = pack8(ra[0], ra[1]);
        *(short8*)&As[tr * LDT + tc + 8] = pack8(ra[2], ra[3]);
#pragma unroll
        for (int h = 0; h < 2; ++h) {
            *(short8*)&Bs[(h * 64 + tr) * LDT + tc]     = pack8(rb[h][0], rb[h][1]);
            *(short8*)&Bs[(h * 64 + tr) * LDT + tc + 8] = pack8(rb[h][2], rb[h][3]);
        }
        __syncthreads();
#pragma unroll
        for (int kk = 0; kk < 64; kk += 32) {
            short8 af[2], bf[4];
#pragma unroll
            for (int m = 0; m < 2; ++m)
                af[m] = *(const short8*)&As[(wr + m * 16 + fr) * LDT + kk + ke];
#pragma unroll
            for (int n = 0; n < 4; ++n)
                bf[n] = *(const short8*)&Bs[(wc + n * 16 + fr) * LDT + kk + ke];
#pragma unroll
            for (int m = 0; m < 2; ++m)
#pragma unroll
                for (int n = 0; n < 4; ++n)
                    acc[m][n] = __builtin_amdgcn_mfma_f32_16x16x32_bf16(
                        __builtin_bit_cast(bf16x8, af[m]),
                        __builtin_bit_cast(bf16x8, bf[n]),
                        acc[m][n], 0, 0, 0);
        }
    }
#pragma unroll
    for (int n = 0; n < 4; ++n) {
        const int col = bn + wc + n * 16 + fr;
        const float bv = bias[col];
#pragma unroll
        for (int m = 0; m < 2; ++m) {
            const int rbase = bm + wr + m * 16 + (lane >> 4) * 4;
#pragma unroll
            for (int r = 0; r < 4; ++r)
                out[(size_t)(rbase + r) * DIM + col] = acc[m][n][r] + bv;
        }
    }
}

__global__ __launch_bounds__(256) void kwalk_fb(const float* __restrict__ X, const float* __restrict__ vec,
                                                const uint4* __restrict__ recs, const int* __restrict__ nlvls,
                                                const unsigned* __restrict__ lvmeta_g,
                                                float* __restrict__ out) {
    __shared__ __align__(16) char smem[SMEMB];
    walk_body(smem, blockIdx.x, X, vec, recs, nlvls, lvmeta_g, out, 1);
}

// ---------------------------------------------------------------------------
extern "C" void kernel_launch(void* const* d_in, const int* in_sizes, int n_in,
                              void* d_out, int out_size, void* d_ws, size_t ws_size,
                              hipStream_t stream) {
    const float* X    = (const float*)d_in[0];
    const float* W    = (const float*)d_in[1];
    const float* bias = (const float*)d_in[2];
    const float* vec  = (const float*)d_in[3];
    const int*   i1   = (const int*)d_in[4];
    const int*   j1   = (const int*)d_in[5];
    const float* c1   = (const float*)d_in[6];
    const float* s1   = (const float*)d_in[7];
    const int*   i2   = (const int*)d_in[8];
    const int*   j2   = (const int*)d_in[9];
    const float* c2   = (const float*)d_in[10];
    const float* s2   = (const float*)d_in[11];
    float* out = (float*)d_out;

    const size_t RD         = (size_t)ROWS * DIM * 4;            // 8 MiB
    const size_t WBB        = (size_t)DIM * DIM * 2;             // 32 MiB
    const size_t XBB        = (size_t)ROWS * DIM * 2;            // 4 MiB
    const size_t recs_bytes = (size_t)NSLOT * SLOTREC * 16;      // 18.9 MiB
    const size_t off_lvm    = recs_bytes + 1024;
    const size_t off_parts  = recs_bytes + 16384;

    // Ksplit=2: 1 walk + 1 GEMM block per CU
    int nks = 0;
    size_t off_wb = 0;
    {
        const size_t need2 = off_parts + 1 * RD + WBB + XBB + RD;
        if (ws_size >= need2) { nks = 2; off_wb = off_parts + 1 * RD; }
    }

    uint4*    recs   = (uint4*)d_ws;
    int*      nlvlsb = (int*)((char*)d_ws + recs_bytes);
    unsigned* lvmeta = (unsigned*)((char*)d_ws + off_lvm);
    float*    parts  = (float*)((char*)d_ws + off_parts);
    short*    wbuf   = (short*)((char*)d_ws + off_wb);
    short*    xbuf   = (short*)((char*)d_ws + off_wb + WBB);
    float*    wkbuf  = (float*)((char*)d_ws + off_wb + WBB + XBB);
    const bool bf = (nks > 0);

    hipLaunchKernelGGL(kfused, dim3(NSLOT + (bf ? (NCVW + NCVX) : 0)), dim3(KT), 0, stream,
                       i1, j1, c1, s1, i2, j2, c2, s2, recs, nlvlsb, lvmeta,
                       bf ? 1 : 0, W, X, wbuf, xbuf);
    if (bf) {
        hipLaunchKernelGGL(kboth, dim3(ROWS / 2 + 128 * nks), dim3(256), 0, stream,
                           X, vec, recs, nlvlsb, lvmeta, wkbuf,
                           xbuf, wbuf, bias, out, parts, nks);
        hipLaunchKernelGGL(kadd, dim3(512), dim3(256), 0, stream,
                           out, wkbuf, parts, nks - 1);
    } else {
        hipLaunchKernelGGL(kgemm_small, dim3(256), dim3(256), 0, stream, X, W, bias, out);
        hipLaunchKernelGGL(kwalk_fb, dim3(ROWS / 2), dim3(256), 0, stream,
                           X, vec, recs, nlvlsb, lvmeta, out);
    }
}

// Round 24
// 181.629 us; speedup vs baseline: 1.1947x; 1.0250x over previous
//
#include <hip/hip_runtime.h>

// KacLayer: out[512][4096] = x @ W^T + b  +  Kac2( vec * Kac1( x ) )
//
//  kfused: blocks 0..23: per-4096-step window scheduler (R23: halved windows,
//          round-stamped atomicMin election -> depth levels; per-wave chunk
//          streams, levels <=2 chunks serial on wave0 w/ barrier elision;
//          exact emission via u16 inverse permutation). Bit-exact reorder.
//          blocks 24..1175: fp32->bf16 convert of W and X into d_ws.
//  kboth : ONE launch, blocks 0..255 = walk path (4 waves / row-pair,
//          level-parallel, light barriers, s_setprio(1); ALL slot metadata
//          preloaded to LDS once -> no per-slot global load + barrier),
//          blocks 256..383 = GEMM path (128x128, BK=64, global_load_lds,
//          swizzled LDS, Ksplit=2).
//  kadd  : out = gemm_out + walkbuf + partial.

#define DIM    4096
#define ROWS   512
#define NSTEPS 49152
#define WSTEPS 4096
#define NW2    (NSTEPS / WSTEPS)   // 12 windows per walk
#define NSLOT  (2 * NW2)           // 24 slots
#define NSG    16                  // rank subgroups (one per ksched wave)
#define CHUNK  128
#define WVN    4                   // walk waves per block
#define PWC    96                  // per-wave chunk capacity per slot
#define SLOTREC (WVN * PWC * CHUNK)   // 49152 records per slot
#define MAXR   64
#define PADI   4096
#define PADJ   4097
#define KT     1024                // scheduler threads
#define SPT    (WSTEPS / KT)       // 4 steps per thread
#define NCVW   1024                // W-convert blocks
#define NCVX   128                 // X-convert blocks
#define SMEMB  39040               // walk: rw 32784 + lvmall 6144 + nlv 96
#define INVCAP ((DIM + WSTEPS) * 2)   // 16384 u16 entries = 128 chunks

typedef short  short8 __attribute__((ext_vector_type(8)));
typedef __bf16 bf16x8 __attribute__((ext_vector_type(8)));
typedef float  f32x4  __attribute__((ext_vector_type(4)));

__device__ inline short f2bf(float f) {
    unsigned u = __builtin_bit_cast(unsigned, f);
    u += 0x7FFFu + ((u >> 16) & 1u);
    return (short)(u >> 16);
}
__device__ inline short8 pack8(float4 a, float4 b) {
    short8 r;
    r[0] = f2bf(a.x); r[1] = f2bf(a.y); r[2] = f2bf(a.z); r[3] = f2bf(a.w);
    r[4] = f2bf(b.x); r[5] = f2bf(b.y); r[6] = f2bf(b.z); r[7] = f2bf(b.w);
    return r;
}
__device__ inline float bitf(unsigned u) { return __builtin_bit_cast(float, u); }
__device__ inline float2 ldrw(const float2* rw, int boff) {
    return *(const float2*)((const char*)rw + boff);
}
__device__ inline void strw(float2* rw, int boff, float2 v) {
    *(float2*)((char*)rw + boff) = v;
}
__device__ inline void gl16(const short* g, short* l) {
    __builtin_amdgcn_global_load_lds((const __attribute__((address_space(1))) unsigned*)g,
                                     (__attribute__((address_space(3))) unsigned*)l, 16, 0, 0);
}

// ---------------------------------------------------------------------------
// 1) fused scheduler (blocks 0..NSLOT-1) + bf16 convert (blocks NSLOT..)
// ---------------------------------------------------------------------------
__global__ __launch_bounds__(KT) void kfused(
    const int* __restrict__ i1, const int* __restrict__ j1,
    const float* __restrict__ c1, const float* __restrict__ s1,
    const int* __restrict__ i2, const int* __restrict__ j2,
    const float* __restrict__ c2, const float* __restrict__ s2,
    uint4* __restrict__ recs, int* __restrict__ nlvls, unsigned* __restrict__ lvmeta_g,
    int doconv, const float* __restrict__ W, const float* __restrict__ X,
    short* __restrict__ wb, short* __restrict__ xb) {

    if (blockIdx.x >= NSLOT) {
        if (!doconv) return;
        const int cb = blockIdx.x - NSLOT;
        const float* src; short* dst; size_t base;
        if (cb < NCVW) { src = W; dst = wb; base = (size_t)cb * 16384; }
        else           { src = X; dst = xb; base = (size_t)(cb - NCVW) * 16384; }
        const size_t o = base + (size_t)threadIdx.x * 16;
        const float4* s4 = (const float4*)(src + o);
        const float4 a0 = s4[0], a1 = s4[1], a2 = s4[2], a3 = s4[3];
        *(short8*)(dst + o)     = pack8(a0, a1);
        *(short8*)(dst + o + 8) = pack8(a2, a3);
        return;
    }

    __shared__ unsigned pool[DIM + WSTEPS];      // 32 KB (tbl+spair; then inv)
    __shared__ unsigned lvrk[WSTEPS];            // 16 KB: rank<<8 | level
    __shared__ int lcnt[MAXR * NSG];             // 4 KB
    __shared__ unsigned lvpk[MAXR], wvbase[MAXR];
    __shared__ unsigned char serf[MAXR];
    __shared__ int nlvlsh;
    __shared__ unsigned totpk;
    __shared__ int ucnt4[WVN], sbase4[WVN];

    unsigned* tbl   = pool;
    unsigned* spair = pool + DIM;

    const int b    = blockIdx.x;
    const int walk = b / NW2;
    const int w    = b % NW2;
    const int t    = threadIdx.x;
    const int gb   = w * WSTEPS;
    const int sg   = t >> 6;

    const int*   I = walk ? i2 : i1;
    const int*   J = walk ? j2 : j1;
    const float* C = walk ? c2 : c1;
    const float* S = walk ? s2 : s1;

    uint4* slotp = recs + (size_t)b * SLOTREC;

    for (int s = t; s < WSTEPS; s += KT)
        spair[s] = (unsigned)I[gb + s] | ((unsigned)J[gb + s] << 16);
    for (int k = t; k < DIM; k += KT) tbl[k] = 0xFFFFFFFFu;
    for (int k = t; k < MAXR * NSG; k += KT) lcnt[k] = 0;
    if (t < MAXR) serf[t] = 0;
    if (t == 0) nlvlsh = 1;
    __syncthreads();

    // ---- election: round-stamped keys; 2 barriers/round; level = depth ----
    unsigned pmask = (1u << SPT) - 1u;
    for (int rr = 0; rr < MAXR; ++rr) {
        const unsigned rk = (unsigned)(MAXR - 1 - rr) << 13;
#pragma unroll
        for (int q = 0; q < SPT; ++q)
            if (pmask & (1u << q)) {
                const int s = q * KT + t;
                const unsigned sp = spair[s];
                const unsigned key = rk | (unsigned)s;
                atomicMin(&tbl[sp & 0xFFFFu], key);
                atomicMin(&tbl[sp >> 16], key);
            }
        __syncthreads();
#pragma unroll
        for (int q = 0; q < SPT; ++q)
            if (pmask & (1u << q)) {
                const int s = q * KT + t;
                const unsigned sp = spair[s];
                const unsigned key = rk | (unsigned)s;
                if (tbl[sp & 0xFFFFu] == key && tbl[sp >> 16] == key) {
                    const int rank = atomicAdd(&lcnt[rr * NSG + sg], 1);
                    lvrk[s] = ((unsigned)rank << 8) | (unsigned)rr;
                    pmask &= ~(1u << q);
                }
            }
        const int np = __syncthreads_count(pmask != 0);
        if (np == 0) break;
    }
#pragma unroll
    for (int q = 0; q < SPT; ++q)
        if (pmask & (1u << q)) {       // statistically unreachable
            const int s = q * KT + t;
            const int rank = atomicAdd(&lcnt[(MAXR - 1) * NSG + sg], 1);
            lvrk[s] = ((unsigned)rank << 8) | (unsigned)(MAXR - 1);
        }
    __syncthreads();

    // ---- layout -----------------------------------------------------------
    if (t < MAXR) {
        int run = 0;
        for (int g = 0; g < NSG; ++g) {
            const int v = lcnt[t * NSG + g];
            lcnt[t * NSG + g] = run;
            run += v;
        }
        const int nch = (run + 127) >> 7;
        unsigned pk = 0;
        if (run > 0 && nch <= 2) { serf[t] = 1; pk = (unsigned)nch; }
        else {
#pragma unroll
            for (int wv = 0; wv < WVN; ++wv)
                pk |= (unsigned)((nch + (WVN - 1 - wv)) >> 2) << (8 * wv);
        }
        lvpk[t] = pk;
        if (run > 0) atomicMax(&nlvlsh, t + 1);
    }
    __syncthreads();
    // packed-u8 exclusive prefix over 64 levels (single wave scan)
    if (t < 64) {
        const int l = t;
        const unsigned w1 = lvpk[l];
        unsigned x1 = w1;
        for (int off = 1; off < 64; off <<= 1) {
            const unsigned v = (unsigned)__shfl_up((int)x1, off);
            if (l >= off) x1 += v;
        }
        wvbase[l] = x1 - w1;
        if (l == 63) totpk = x1;
    }
    __syncthreads();
    if (t < WVN) {
        int u = (int)((totpk >> (8 * t)) & 0xFFu);
        ucnt4[t] = (u > PWC) ? PWC : u;
    }
    if (t < MAXR - 1) {
        if (serf[t] && serf[t + 1]) lvpk[t] |= 0x80000000u;
    }
    __syncthreads();
    if (t == 0) {
        sbase4[0] = 0;
        for (int v = 1; v < WVN; ++v) sbase4[v] = sbase4[v - 1] + ucnt4[v - 1];
        nlvls[b] = nlvlsh;
    }
    if (t < MAXR) lvmeta_g[b * MAXR + t] = lvpk[t];
    __syncthreads();

    // ---- inv table over used positions (reuses pool) ----------------------
    const int usedtot = sbase4[WVN - 1] + ucnt4[WVN - 1];
    for (int k = t; k < usedtot * 64; k += KT) pool[k] = 0xFFFFFFFFu;
    __syncthreads();
    unsigned short* inv = (unsigned short*)pool;
#pragma unroll
    for (int q = 0; q < SPT; ++q) {
        const int s = q * KT + t;
        const unsigned v = lvrk[s];
        const int lvl  = (int)(v & 0xFFu);
        const int rank = (int)(v >> 8) + lcnt[lvl * NSG + sg];
        const int cl   = rank >> 7;
        const int pos  = rank & 127;
        int wv2, wc2;
        if (serf[lvl]) { wv2 = 0; wc2 = cl; }
        else           { wv2 = cl & (WVN - 1); wc2 = cl >> 2; }
        const int pch = (int)((wvbase[lvl] >> (8 * wv2)) & 0xFFu) + wc2;
        if (pch < ucnt4[wv2]) {
            const int ipos = (sbase4[wv2] + pch) * 128 + pos;
            if (ipos < INVCAP) inv[ipos] = (unsigned short)s;
        }
    }
    __syncthreads();

    // ---- coalesced exact emission -----------------------------------------
    const uint4 padrec = { (unsigned)(PADI * 8), 0x3F800000u, 0u, (unsigned)(PADJ * 8) };
    for (int wv = 0; wv < WVN; ++wv) {
        const int npos = ucnt4[wv] * 128;
        const int ibase = sbase4[wv] * 128;
        uint4* dst = slotp + (size_t)wv * (PWC * CHUNK);
        for (int p = t; p < npos; p += KT) {
            const unsigned s = inv[ibase + p];
            uint4 r = padrec;
            if (s != 0xFFFFu) {
                const int g = gb + (int)s;
                r.x = (unsigned)(I[g] * 8);
                r.y = __builtin_bit_cast(unsigned, C[g]);
                r.z = __builtin_bit_cast(unsigned, S[g]);
                r.w = (unsigned)(J[g] * 8);
            }
            dst[p] = r;
        }
    }
}

// ---------------------------------------------------------------------------
// walk body: ALL slot metadata preloaded to LDS once (no per-slot load+barrier)
// ---------------------------------------------------------------------------
__device__ void walk_body(char* smem, int pr,
                          const float* __restrict__ X, const float* __restrict__ vec,
                          const uint4* __restrict__ recs, const int* __restrict__ nlvls,
                          const unsigned* __restrict__ lvmeta_g,
                          float* __restrict__ dstbuf, int directadd) {
    float2* rw = (float2*)smem;
    unsigned* lvmall = (unsigned*)(smem + (DIM + 2) * 8);          // NSLOT*MAXR
    int* nlv = (int*)(smem + (DIM + 2) * 8 + NSLOT * MAXR * 4);    // NSLOT
    const int tid  = threadIdx.x;
    const int wv   = tid >> 6;
    const int lane = tid & 63;
    const int rA   = pr * 2, rB = pr * 2 + 1;

    {
        const float4* xa = (const float4*)(X + (size_t)rA * DIM);
        const float4* xb = (const float4*)(X + (size_t)rB * DIM);
        for (int c4 = tid; c4 < DIM / 4; c4 += 256) {
            const float4 a = xa[c4], b = xb[c4];
            rw[c4 * 4 + 0] = make_float2(a.x, b.x);
            rw[c4 * 4 + 1] = make_float2(a.y, b.y);
            rw[c4 * 4 + 2] = make_float2(a.z, b.z);
            rw[c4 * 4 + 3] = make_float2(a.w, b.w);
        }
        if (tid < 2) rw[DIM + tid] = make_float2(0.f, 0.f);
        // preload ALL per-slot metadata once
        for (int k = tid; k < NSLOT * MAXR; k += 256) lvmall[k] = lvmeta_g[k];
        if (tid < NSLOT) nlv[tid] = nlvls[tid];
    }
    __syncthreads();

    __builtin_amdgcn_s_setprio(1);     // latency-critical path: win arbitration

    for (int slot = 0; slot < NSLOT; ++slot) {
        if (slot == NW2) {
            const float4* v4 = (const float4*)vec;
            for (int c4 = tid; c4 < DIM / 4; c4 += 256) {
                const float4 v = v4[c4];
#pragma unroll
                for (int q = 0; q < 4; ++q) {
                    float2 tv = rw[c4 * 4 + q];
                    const float sc = (q == 0) ? v.x : (q == 1) ? v.y : (q == 2) ? v.z : v.w;
                    tv.x *= sc; tv.y *= sc;
                    rw[c4 * 4 + q] = tv;
                }
            }
            __syncthreads();           // all lanes see scaled row
        }
        const unsigned* lvm = lvmall + slot * MAXR;
        const int nlvl = nlv[slot];

        const uint4* wbase = recs + (size_t)slot * SLOTREC + (size_t)wv * (PWC * CHUNK);
        uint4 r0A = wbase[lane],       r0B = wbase[64 + lane];
        uint4 r1A = wbase[128 + lane], r1B = wbase[192 + lane];
        uint4 r2A = wbase[256 + lane], r2B = wbase[320 + lane];
        int t = 0;

        for (int lvl = 0; lvl < nlvl; ++lvl) {
            const unsigned mm = lvm[lvl];
            int n = (int)((mm >> (wv * 8)) & 0xFFu);
            if (wv == 3) n &= 0x7F;
            for (int it = 0; it < n; ++it) {
                int kc = t + 3; if (kc > PWC - 1) kc = PWC - 1;
                const uint4 mA = wbase[(size_t)kc * CHUNK + lane];
                const uint4 mB = wbase[(size_t)kc * CHUNK + 64 + lane];

                const int   ia = (int)r0A.x, ja = (int)r0A.w;
                const int   ib = (int)r0B.x, jb = (int)r0B.w;
                const float ca = bitf(r0A.y), sa = bitf(r0A.z);
                const float cb = bitf(r0B.y), sb = bitf(r0B.z);
                const float2 gai = ldrw(rw, ia), gaj = ldrw(rw, ja);
                const float2 gbi = ldrw(rw, ib), gbj = ldrw(rw, jb);

                float2 wia, wja, wib, wjb;
                wia.x = fmaf(ca, gai.x,  sa * gaj.x);
                wia.y = fmaf(ca, gai.y,  sa * gaj.y);
                wja.x = fmaf(ca, gaj.x, -sa * gai.x);
                wja.y = fmaf(ca, gaj.y, -sa * gai.y);
                wib.x = fmaf(cb, gbi.x,  sb * gbj.x);
                wib.y = fmaf(cb, gbi.y,  sb * gbj.y);
                wjb.x = fmaf(cb, gbj.x, -sb * gbi.x);
                wjb.y = fmaf(cb, gbj.y, -sb * gbi.y);
                strw(rw, ia, wia); strw(rw, ja, wja);
                strw(rw, ib, wib); strw(rw, jb, wjb);

                r0A = r1A; r0B = r1B;
                r1A = r2A; r1B = r2B;
                r2A = mA;  r2B = mB;
                ++t;
            }
            if (!(mm & 0x80000000u)) {
                __builtin_amdgcn_sched_barrier(0);
                asm volatile("s_waitcnt lgkmcnt(0)" ::: "memory");
                __builtin_amdgcn_s_barrier();
                __builtin_amdgcn_sched_barrier(0);
            }
        }
    }

    __builtin_amdgcn_s_setprio(0);

    float4* oa = (float4*)(dstbuf + (size_t)rA * DIM);
    float4* ob = (float4*)(dstbuf + (size_t)rB * DIM);
    for (int c4 = tid; c4 < DIM / 4; c4 += 256) {
        const float2 p0 = rw[c4 * 4 + 0], p1 = rw[c4 * 4 + 1];
        const float2 p2 = rw[c4 * 4 + 2], p3 = rw[c4 * 4 + 3];
        float4 ta, tb;
        if (directadd) { ta = oa[c4]; tb = ob[c4]; }
        else           { ta = (float4){0,0,0,0}; tb = (float4){0,0,0,0}; }
        ta.x += p0.x; ta.y += p1.x; ta.z += p2.x; ta.w += p3.x;
        tb.x += p0.y; tb.y += p1.y; tb.z += p2.y; tb.w += p3.y;
        oa[c4] = ta; ob[c4] = tb;
    }
}

// ---------------------------------------------------------------------------
// GEMM body (bf16, global_load_lds staging, BK=64)
// ---------------------------------------------------------------------------
__device__ void gemm_body(char* smem, int bid,
                          const short* __restrict__ Xb, const short* __restrict__ Wb,
                          const float* __restrict__ bias, float* __restrict__ out,
                          float* __restrict__ parts, int nks) {
    short* As = (short*)smem;
    short* Bs = As + 128 * 64;
    const int ks   = bid % nks;
    const int tile = bid / nks;
    const int bm   = (tile >> 5) * 128;
    const int bn   = (tile & 31) * 128;
    const int tid  = threadIdx.x;
    const int lane = tid & 63;
    const int wv   = tid >> 6;
    const int wr   = (wv >> 1) * 64;
    const int wc   = (wv & 1) * 64;
    const int fr   = lane & 15;
    const int ke   = (lane >> 4) * 8;

    f32x4 acc[4][4];
#pragma unroll
    for (int m = 0; m < 4; ++m)
#pragma unroll
        for (int n = 0; n < 4; ++n) acc[m][n] = (f32x4){0.f, 0.f, 0.f, 0.f};

    const int lrow = lane >> 3;
    const int scol = (((lane & 7) ^ (lrow & 7)) << 3);
    const short* gx = Xb + (size_t)(bm + wv * 32 + lrow) * DIM + scol;
    const short* gw = Wb + (size_t)(bn + wv * 32 + lrow) * DIM + scol;
    short* lA = As + wv * 2048;
    short* lB = Bs + wv * 2048;

    const int nkt   = (DIM / 64) / nks;
    const int kbase = ks * (DIM / nks);
    for (int kt = 0; kt < nkt; ++kt) {
        const int k0 = kbase + kt * 64;
        __syncthreads();
#pragma unroll
        for (int q = 0; q < 4; ++q) {
            gl16(gx + (size_t)(q * 8) * DIM + k0, lA + q * 512);
            gl16(gw + (size_t)(q * 8) * DIM + k0, lB + q * 512);
        }
        __syncthreads();
#pragma unroll
        for (int kk = 0; kk < 64; kk += 32) {
            const int sb = (kk + ke) >> 3;
            short8 af[4], bf[4];
#pragma unroll
            for (int m = 0; m < 4; ++m) {
                const int R = wr + m * 16 + fr;
                af[m] = *(const short8*)&As[R * 64 + ((sb ^ (R & 7)) << 3)];
            }
#pragma unroll
            for (int n = 0; n < 4; ++n) {
                const int R = wc + n * 16 + fr;
                bf[n] = *(const short8*)&Bs[R * 64 + ((sb ^ (R & 7)) << 3)];
            }
#pragma unroll
            for (int m = 0; m < 4; ++m)
#pragma unroll
                for (int n = 0; n < 4; ++n)
                    acc[m][n] = __builtin_amdgcn_mfma_f32_16x16x32_bf16(
                        __builtin_bit_cast(bf16x8, af[m]),
                        __builtin_bit_cast(bf16x8, bf[n]),
                        acc[m][n], 0, 0, 0);
        }
    }
    float* dst = ks ? (parts + (size_t)(ks - 1) * ROWS * DIM) : out;
#pragma unroll
    for (int n = 0; n < 4; ++n) {
        const int col = bn + wc + n * 16 + fr;
        const float bv = ks ? 0.f : bias[col];
#pragma unroll
        for (int m = 0; m < 4; ++m) {
            const int rbase = bm + wr + m * 16 + (lane >> 4) * 4;
#pragma unroll
            for (int r = 0; r < 4; ++r)
                dst[(size_t)(rbase + r) * DIM + col] = acc[m][n][r] + bv;
        }
    }
}

// ---------------------------------------------------------------------------
// 2) kboth: walk (blocks 0..255) + GEMM (blocks 256..) in one launch
// ---------------------------------------------------------------------------
__global__ __launch_bounds__(256) void kboth(
    const float* __restrict__ X, const float* __restrict__ vec,
    const uint4* __restrict__ recs, const int* __restrict__ nlvls,
    const unsigned* __restrict__ lvmeta_g, float* __restrict__ walkbuf,
    const short* __restrict__ Xb, const short* __restrict__ Wb,
    const float* __restrict__ bias, float* __restrict__ out,
    float* __restrict__ parts, int nks) {
    __shared__ __align__(16) char smem[SMEMB];
    if (blockIdx.x < ROWS / 2)
        walk_body(smem, blockIdx.x, X, vec, recs, nlvls, lvmeta_g, walkbuf, 0);
    else
        gemm_body(smem, blockIdx.x - ROWS / 2, Xb, Wb, bias, out, parts, nks);
}

// ---------------------------------------------------------------------------
// 3) kadd: out += walkbuf + sum(parts)
// ---------------------------------------------------------------------------
__global__ __launch_bounds__(256) void kadd(float* __restrict__ out,
                                            const float* __restrict__ walkbuf,
                                            const float* __restrict__ parts, int nparts) {
    const size_t N = (size_t)ROWS * DIM / 4;
    const size_t i0 = (size_t)blockIdx.x * 256 + threadIdx.x;
    float4* o4 = (float4*)out;
    const float4* w4 = (const float4*)walkbuf;
    const float4* p4 = (const float4*)parts;
    for (size_t i = i0; i < N; i += (size_t)gridDim.x * 256) {
        float4 t = o4[i];
        const float4 s = w4[i];
        t.x += s.x; t.y += s.y; t.z += s.z; t.w += s.w;
        for (int p = 0; p < nparts; ++p) {
            const float4 a = p4[i + (size_t)p * N];
            t.x += a.x; t.y += a.y; t.z += a.z; t.w += a.w;
        }
        o4[i] = t;
    }
}

// ---------------------------------------------------------------------------
// fallback kernels (small workspace): fp32-staging GEMM + direct-add walk
// ---------------------------------------------------------------------------
#define LDT 72
__global__ __launch_bounds__(256) void kgemm_small(const float* __restrict__ X, const float* __restrict__ W,
                                                   const float* __restrict__ bias, float* __restrict__ out) {
    __shared__ short As[64 * LDT];
    __shared__ short Bs[128 * LDT];
    const int tid  = threadIdx.x;
    const int bn   = (blockIdx.x & 31) * 128;
    const int bm   = (blockIdx.x >> 5) * 64;
    const int lane = tid & 63;
    const int wv   = tid >> 6;
    const int wr   = (wv >> 1) * 32;
    const int wc   = (wv & 1) * 64;
    const int fr   = lane & 15;
    const int ke   = (lane >> 4) * 8;

    f32x4 acc[2][4];
#pragma unroll
    for (int m = 0; m < 2; ++m)
#pragma unroll
        for (int n = 0; n < 4; ++n) acc[m][n] = (f32x4){0.f, 0.f, 0.f, 0.f};

    const int tr = tid >> 2;
    const int tc = (tid & 3) << 4;

    for (int kt = 0; kt < DIM / 64; ++kt) {
        const int k0 = kt * 64;
        float4 ra[4], rb[2][4];
        {
            const float4* ga = (const float4*)(X + (size_t)(bm + tr) * DIM + k0 + tc);
#pragma unroll
            for (int q = 0; q < 4; ++q) ra[q] = ga[q];
#pragma unroll
            for (int h = 0; h < 2; ++h) {
                const float4* gw = (const float4*)(W + (size_t)(bn + h * 64 + tr) * DIM + k0 + tc);
#pragma unroll
                for (int q = 0; q < 4; ++q) rb[h][q] = gw[q];
            }
        }
        __syncthreads();
        *(short8*)&As[tr * LDT + tc]     = pack8(ra[0], ra[1]);
        *(short8*)&As[tr * LDT + tc + 8] = pack8(ra[2], ra[3]);
#pragma unroll
        for (int h = 0; h < 2; ++h) {
            *(short8*)&Bs[(h * 64 + tr) * LDT + tc]     = pack8(rb[h][0], rb[h][1]);
            *(short8*)&Bs[(h * 64 + tr) * LDT + tc + 8] = pack8(rb[h][2], rb[h][3]);
        }
        __syncthreads();
#pragma unroll
        for (int kk = 0; kk < 64; kk += 32) {
            short8 af[2], bf[4];
#pragma unroll
            for (int m = 0; m < 2; ++m)
                af[m] = *(const short8*)&As[(wr + m * 16 + fr) * LDT + kk + ke];
#pragma unroll
            for (int n = 0; n < 4; ++n)
                bf[n] = *(const short8*)&Bs[(wc + n * 16 + fr) * LDT + kk + ke];
#pragma unroll
            for (int m = 0; m < 2; ++m)
#pragma unroll
                for (int n = 0; n < 4; ++n)
                    acc[m][n] = __builtin_amdgcn_mfma_f32_16x16x32_bf16(
                        __builtin_bit_cast(bf16x8, af[m]),
                        __builtin_bit_cast(bf16x8, bf[n]),
                        acc[m][n], 0, 0, 0);
        }
    }
#pragma unroll
    for (int n = 0; n < 4; ++n) {
        const int col = bn + wc + n * 16 + fr;
        const float bv = bias[col];
#pragma unroll
        for (int m = 0; m < 2; ++m) {
            const int rbase = bm + wr + m * 16 + (lane >> 4) * 4;
#pragma unroll
            for (int r = 0; r < 4; ++r)
                out[(size_t)(rbase + r) * DIM + col] = acc[m][n][r] + bv;
        }
    }
}

__global__ __launch_bounds__(256) void kwalk_fb(const float* __restrict__ X, const float* __restrict__ vec,
                                                const uint4* __restrict__ recs, const int* __restrict__ nlvls,
                                                const unsigned* __restrict__ lvmeta_g,
                                                float* __restrict__ out) {
    __shared__ __align__(16) char smem[SMEMB];
    walk_body(smem, blockIdx.x, X, vec, recs, nlvls, lvmeta_g, out, 1);
}

// ---------------------------------------------------------------------------
extern "C" void kernel_launch(void* const* d_in, const int* in_sizes, int n_in,
                              void* d_out, int out_size, void* d_ws, size_t ws_size,
                              hipStream_t stream) {
    const float* X    = (const float*)d_in[0];
    const float* W    = (const float*)d_in[1];
    const float* bias = (const float*)d_in[2];
    const float* vec  = (const float*)d_in[3];
    const int*   i1   = (const int*)d_in[4];
    const int*   j1   = (const int*)d_in[5];
    const float* c1   = (const float*)d_in[6];
    const float* s1   = (const float*)d_in[7];
    const int*   i2   = (const int*)d_in[8];
    const int*   j2   = (const int*)d_in[9];
    const float* c2   = (const float*)d_in[10];
    const float* s2   = (const float*)d_in[11];
    float* out = (float*)d_out;

    const size_t RD         = (size_t)ROWS * DIM * 4;            // 8 MiB
    const size_t WBB        = (size_t)DIM * DIM * 2;             // 32 MiB
    const size_t XBB        = (size_t)ROWS * DIM * 2;            // 4 MiB
    const size_t recs_bytes = (size_t)NSLOT * SLOTREC * 16;      // 18.9 MiB
    const size_t off_lvm    = recs_bytes + 1024;
    const size_t off_parts  = recs_bytes + 16384;

    // Ksplit=2: 1 walk + 1 GEMM block per CU
    int nks = 0;
    size_t off_wb = 0;
    {
        const size_t need2 = off_parts + 1 * RD + WBB + XBB + RD;
        if (ws_size >= need2) { nks = 2; off_wb = off_parts + 1 * RD; }
    }

    uint4*    recs   = (uint4*)d_ws;
    int*      nlvlsb = (int*)((char*)d_ws + recs_bytes);
    unsigned* lvmeta = (unsigned*)((char*)d_ws + off_lvm);
    float*    parts  = (float*)((char*)d_ws + off_parts);
    short*    wbuf   = (short*)((char*)d_ws + off_wb);
    short*    xbuf   = (short*)((char*)d_ws + off_wb + WBB);
    float*    wkbuf  = (float*)((char*)d_ws + off_wb + WBB + XBB);
    const bool bf = (nks > 0);

    hipLaunchKernelGGL(kfused, dim3(NSLOT + (bf ? (NCVW + NCVX) : 0)), dim3(KT), 0, stream,
                       i1, j1, c1, s1, i2, j2, c2, s2, recs, nlvlsb, lvmeta,
                       bf ? 1 : 0, W, X, wbuf, xbuf);
    if (bf) {
        hipLaunchKernelGGL(kboth, dim3(ROWS / 2 + 128 * nks), dim3(256), 0, stream,
                           X, vec, recs, nlvlsb, lvmeta, wkbuf,
                           xbuf, wbuf, bias, out, parts, nks);
        hipLaunchKernelGGL(kadd, dim3(512), dim3(256), 0, stream,
                           out, wkbuf, parts, nks - 1);
    } else {
        hipLaunchKernelGGL(kgemm_small, dim3(256), dim3(256), 0, stream, X, W, bias, out);
        hipLaunchKernelGGL(kwalk_fb, dim3(ROWS / 2), dim3(256), 0, stream,
                           X, vec, recs, nlvlsb, lvmeta, out);
    }
}